// Round 7
// baseline (398.146 us; speedup 1.0000x reference)
//
#include <hip/hip_runtime.h>
#include <math.h>

// Problem constants: B=1, H=W=64 (N=4096), C=768, 12 heads x hd=64.
#define NHEADS 12
#define NTOK 4096
#define LOG2E 1.44269504f

typedef __attribute__((ext_vector_type(8))) short bf8v;   // 8 x bf16 (4 VGPR)
typedef __attribute__((ext_vector_type(4))) float f4v;    // MFMA C/D frag

__device__ __forceinline__ unsigned short f2bf(float f) {
  unsigned int u = __float_as_uint(f);
  u += 0x7fffu + ((u >> 16) & 1u);   // RNE
  return (unsigned short)(u >> 16);
}
__device__ __forceinline__ float bf2f(unsigned short h) {
  return __uint_as_float(((unsigned int)h) << 16);
}
__device__ __forceinline__ bf8v pack8(float4 a, float4 b) {
  bf8v v;
  v[0] = (short)f2bf(a.x); v[1] = (short)f2bf(a.y);
  v[2] = (short)f2bf(a.z); v[3] = (short)f2bf(a.w);
  v[4] = (short)f2bf(b.x); v[5] = (short)f2bf(b.y);
  v[6] = (short)f2bf(b.z); v[7] = (short)f2bf(b.w);
  return v;
}
// pack two f32 (round via +0x8000) into (hi|lo) bf16 pair
__device__ __forceinline__ unsigned pkbf(float hi, float lo) {
  return __builtin_amdgcn_perm(__float_as_uint(hi) + 0x8000u,
                               __float_as_uint(lo) + 0x8000u, 0x07060302u);
}

// ---------------------------------------------------------------------------
// cvt: fp32 -> bf16 elementwise (x), 8 elems/thread
// ---------------------------------------------------------------------------
__global__ __launch_bounds__(256) void cvt_kernel(
    const float* __restrict__ in, short* __restrict__ out)
{
    const size_t i = ((size_t)blockIdx.x * 256 + threadIdx.x) * 8;
    float4 a = *(const float4*)(in + i);
    float4 b = *(const float4*)(in + i + 4);
    *(bf8v*)(out + i) = pack8(a, b);
}

// ---------------------------------------------------------------------------
// cvt_rpw: rel_pos_w fp32 [127][64] -> bf16 [128][64] (row 127 zeroed)
// ---------------------------------------------------------------------------
__global__ __launch_bounds__(256) void cvt_rpw_kernel(
    const float* __restrict__ in, short* __restrict__ out)
{
    const int idx = blockIdx.x * 256 + threadIdx.x;   // grid 32 -> 8192
    const float v = (idx < 127 * 64) ? in[idx] : 0.f;
    out[idx] = (short)f2bf(v);
}

// ---------------------------------------------------------------------------
// tcvt: fp32 in[R][C] -> bf16 out[C][R] (64x64 LDS tiles)
// ---------------------------------------------------------------------------
__global__ __launch_bounds__(256) void tcvt_kernel(
    const float* __restrict__ in, short* __restrict__ out, int R, int C)
{
    __shared__ float Ts[64][65];
    const int bc = blockIdx.x * 64, br = blockIdx.y * 64, t = threadIdx.x;
    {
        const int r = t >> 2, c0 = (t & 3) * 16;
        const float* src = in + (size_t)(br + r) * C + bc + c0;
#pragma unroll
        for (int i = 0; i < 4; ++i) {
            float4 a = *(const float4*)(src + 4 * i);
            Ts[r][c0 + 4 * i + 0] = a.x;
            Ts[r][c0 + 4 * i + 1] = a.y;
            Ts[r][c0 + 4 * i + 2] = a.z;
            Ts[r][c0 + 4 * i + 3] = a.w;
        }
    }
    __syncthreads();
    const int c = t >> 2, r0 = (t & 3) * 16;
    short* dst = out + (size_t)(bc + c) * R + br + r0;
#pragma unroll
    for (int p = 0; p < 2; ++p) {
        bf8v v;
#pragma unroll
        for (int i = 0; i < 8; ++i) v[i] = (short)f2bf(Ts[r0 + p * 8 + i][c]);
        *(bf8v*)(dst + p * 8) = v;
    }
}

// ---------------------------------------------------------------------------
// QKV GEMM (MFMA bf16): C[m][n] = xh[m][k] @ wT[n][k]^T + bias[n]
// ---------------------------------------------------------------------------
__device__ __forceinline__ void gload_lds16(const void* g, void* l) {
  __builtin_amdgcn_global_load_lds(
      (const __attribute__((address_space(1))) void*)g,
      (__attribute__((address_space(3))) void*)l, 16, 0, 0);
}

__global__ __launch_bounds__(256) void qkv_mfma_kernel(
    const short* __restrict__ xh, const short* __restrict__ wT,
    const float* __restrict__ bias, short* __restrict__ qbh,
    short* __restrict__ kbh, short* __restrict__ vbT)
{
    __shared__ __align__(16) short As[128 * 32];
    __shared__ __align__(16) short Bs[128 * 32];
    const int t = threadIdx.x;
    const int w = t >> 6, lane = t & 63;
    const int l15 = lane & 15, l4 = lane >> 4;
    const int wr = w >> 1, wc = w & 1;
    const int row0 = blockIdx.y * 128, col0 = blockIdx.x * 128;
    const int ldr = lane >> 2;
    const int ldk = (lane & 3) * 8;

    f4v acc[4][4] = {};
    const short* aBase = xh + (size_t)(row0 + w * 32 + ldr) * 768 + ldk;
    const short* bBase = wT + (size_t)(col0 + w * 32 + ldr) * 768 + ldk;

    for (int kk = 0; kk < 768; kk += 32) {
        __syncthreads();
#pragma unroll
        for (int c = 0; c < 2; ++c) {
            gload_lds16(aBase + (size_t)c * 16 * 768 + kk,
                        &As[(w * 32 + c * 16) * 32]);
            gload_lds16(bBase + (size_t)c * 16 * 768 + kk,
                        &Bs[(w * 32 + c * 16) * 32]);
        }
        __syncthreads();
        bf8v af[4], bg[4];
#pragma unroll
        for (int i = 0; i < 4; ++i) {
            af[i] = *(const bf8v*)&As[(wr * 64 + 16 * i + l15) * 32 + l4 * 8];
            bg[i] = *(const bf8v*)&Bs[(wc * 64 + 16 * i + l15) * 32 + l4 * 8];
        }
#pragma unroll
        for (int i = 0; i < 4; ++i)
#pragma unroll
            for (int j = 0; j < 4; ++j)
                acc[i][j] = __builtin_amdgcn_mfma_f32_16x16x32_bf16(
                    af[i], bg[j], acc[i][j], 0, 0, 0);
    }

#pragma unroll
    for (int j = 0; j < 4; ++j) {
        const int n = col0 + wc * 64 + 16 * j + l15;
        const int s = n / 768;            // block-uniform (768 = 6*128)
        const int rm = n - s * 768;
        const int h = rm >> 6, d = rm & 63;
        const float bv = bias[n];
        if (s == 2) {
            short* vdst = vbT + (size_t)(h * 64 + d) * NTOK;
#pragma unroll
            for (int i = 0; i < 4; ++i) {
                const int m = row0 + wr * 64 + 16 * i + l4 * 4;
                short4 pv;
                pv.x = (short)f2bf(acc[i][j][0] + bv);
                pv.y = (short)f2bf(acc[i][j][1] + bv);
                pv.z = (short)f2bf(acc[i][j][2] + bv);
                pv.w = (short)f2bf(acc[i][j][3] + bv);
                *(short4*)(vdst + m) = pv;
            }
        } else {
            short* dst = (s == 0) ? qbh : kbh;
#pragma unroll
            for (int i = 0; i < 4; ++i) {
                const int m = row0 + wr * 64 + 16 * i + l4 * 4;
#pragma unroll
                for (int r = 0; r < 4; ++r)
                    dst[((size_t)h * NTOK + m + r) * 64 + d] =
                        (short)f2bf(acc[i][j][r] + bv);
            }
        }
    }
}

// ---------------------------------------------------------------------------
// relu: U[j][qw] = sum_d rpwb[j][d] * Q[h][qh*64+qw][d]  (MFMA, per (h,qh))
// then rWb[h][qh*64+qw][kw] = bf16( LOG2E * U[qw+63-kw][qw] )
// ---------------------------------------------------------------------------
__global__ __launch_bounds__(256) void relu_kernel(
    const short* __restrict__ qbh, const short* __restrict__ rpwb,
    short* __restrict__ rWb)
{
    __shared__ float Us[128][65];
    const int h = blockIdx.x, qh = blockIdx.y;
    const int t = threadIdx.x, w = t >> 6, lane = t & 63;
    const int l15 = lane & 15, l4 = lane >> 4;
    const size_t hB = (size_t)h * NTOK * 64;

    bf8v bq[4][2];
#pragma unroll
    for (int nt = 0; nt < 4; ++nt) {
        const short* qs = qbh + hB + (size_t)(qh * 64 + nt * 16 + l15) * 64;
#pragma unroll
        for (int s = 0; s < 2; ++s)
            bq[nt][s] = *(const bf8v*)(qs + s * 32 + l4 * 8);
    }
    bf8v aw[2][2];
#pragma unroll
    for (int mi = 0; mi < 2; ++mi) {
        const short* as = rpwb + (size_t)((w * 2 + mi) * 16 + l15) * 64;
#pragma unroll
        for (int s = 0; s < 2; ++s)
            aw[mi][s] = *(const bf8v*)(as + s * 32 + l4 * 8);
    }
    f4v U[2][4] = {};
#pragma unroll
    for (int mi = 0; mi < 2; ++mi)
#pragma unroll
        for (int nt = 0; nt < 4; ++nt)
#pragma unroll
            for (int s = 0; s < 2; ++s)
                U[mi][nt] = __builtin_amdgcn_mfma_f32_16x16x32_bf16(
                    aw[mi][s], bq[nt][s], U[mi][nt], 0, 0, 0);
#pragma unroll
    for (int mi = 0; mi < 2; ++mi)
#pragma unroll
        for (int nt = 0; nt < 4; ++nt)
#pragma unroll
            for (int r = 0; r < 4; ++r)
                Us[(w * 2 + mi) * 16 + l4 * 4 + r][nt * 16 + l15] =
                    U[mi][nt][r];
    __syncthreads();
    const int kw = t & 63, q0 = t >> 6;
#pragma unroll
    for (int i = 0; i < 16; ++i) {
        const int q = q0 * 16 + i;
        rWb[hB + (size_t)(qh * 64 + q) * 64 + kw] =
            (short)f2bf(Us[q + 63 - kw][q] * LOG2E);
    }
}

// ---------------------------------------------------------------------------
// Flash attention v3: S^T formulation, TQ=128, TK=128, K-split 2, no-max
// softmax. Block = (128-row q-tile, head, k-half), 4 waves. Each lane owns
// one softmax row per q-group (q = qg*64 + 16w + lane&15). Ks/Vt fragments
// are reused across the two q-groups (2x LDS amortization + 2 independent
// chains per wave for ILP). Partials (unnormalized O, l) combined later.
// ---------------------------------------------------------------------------
__global__ __launch_bounds__(256, 3) void flash_mfma_kernel(
    const short* __restrict__ qbh, const short* __restrict__ kbh,
    const short* __restrict__ vbT, const short* __restrict__ rWb,
    const float* __restrict__ rph, short* __restrict__ Opart,
    float* __restrict__ lpart)
{
    __shared__ __align__(16) short Ks[128][68];    // [tok][d] bf16
    __shared__ __align__(16) short Vt[64][132];    // [d][tok] bf16
    __shared__ short relHs[32][132];               // [kh_local][q_local] bf16

    const int t = threadIdx.x;
    const int qt2 = blockIdx.x, head = blockIdx.y, z = blockIdx.z;
    const int row0 = qt2 * 128;
    const int lane = t & 63, w = t >> 6;
    const int l15 = lane & 15, l4 = lane >> 4;
    const size_t hB = (size_t)head * NTOK * 64;
    const int tokBase = z * 2048;
    const float SC = 0.125f * LOG2E;

    // Q as B-fragments + packed-bf16 relW rows, per q-group
    bf8v bQ[2][2];
    uint2 rwp[2][4];
#pragma unroll
    for (int qg = 0; qg < 2; ++qg) {
        const int q = row0 + qg * 64 + 16 * w + l15;
        const short* qsrc = qbh + hB + (size_t)q * 64;
#pragma unroll
        for (int s = 0; s < 2; ++s)
            bQ[qg][s] = *(const bf8v*)(qsrc + s * 32 + l4 * 8);
        const short* rsrc = rWb + hB + (size_t)q * 64;
#pragma unroll
        for (int nt = 0; nt < 4; ++nt)
            rwp[qg][nt] = *(const uint2*)(rsrc + nt * 16 + l4 * 4);
    }

    // stage reversed rph slices (x LOG2E) for both q-halves into Ks scratch
    {
        const int row = t >> 2;            // 0..63
        const int qg = row >> 5, rr = row & 31;
        const int d0 = (t & 3) * 16;
        const int qh = 2 * qt2 + qg;
        const int kh = (tokBase >> 6) + rr;
        const float* src = rph + (size_t)(qh + 63 - kh) * 64 + d0;
        float4 a0 = *(const float4*)(src);
        float4 a1 = *(const float4*)(src + 4);
        float4 a2 = *(const float4*)(src + 8);
        float4 a3 = *(const float4*)(src + 12);
        a0.x *= LOG2E; a0.y *= LOG2E; a0.z *= LOG2E; a0.w *= LOG2E;
        a1.x *= LOG2E; a1.y *= LOG2E; a1.z *= LOG2E; a1.w *= LOG2E;
        a2.x *= LOG2E; a2.y *= LOG2E; a2.z *= LOG2E; a2.w *= LOG2E;
        a3.x *= LOG2E; a3.y *= LOG2E; a3.z *= LOG2E; a3.w *= LOG2E;
        *(bf8v*)&Ks[row][d0] = pack8(a0, a1);
        *(bf8v*)&Ks[row][d0 + 8] = pack8(a2, a3);
    }
    // K/V register prefetch for iter 0
    const int sx = t >> 2;            // K token row / V d-row
    const int sck = (t & 3) * 16;     // K d-offset
    const int scv = (t & 3) * 32;     // V token-offset
    const short* kptr = kbh + hB + (size_t)(tokBase + sx) * 64 + sck;
    const short* vptr = vbT + ((size_t)head * 64 + sx) * NTOK + tokBase + scv;
    bf8v kpf[4], vpf[4];
    kpf[0] = *(const bf8v*)(kptr);
    kpf[1] = *(const bf8v*)(kptr + 8);
    kpf[2] = *(const bf8v*)(kptr + 64 * 64);
    kpf[3] = *(const bf8v*)(kptr + 64 * 64 + 8);
    vpf[0] = *(const bf8v*)(vptr);
    vpf[1] = *(const bf8v*)(vptr + 8);
    vpf[2] = *(const bf8v*)(vptr + 16);
    vpf[3] = *(const bf8v*)(vptr + 24);

    __syncthreads();
    // relH GEMM: relHs[kh_local][q_local] = (rph_rev . Q^T) per q-group
#pragma unroll
    for (int qg = 0; qg < 2; ++qg)
#pragma unroll
        for (int mt = 0; mt < 2; ++mt) {
            f4v c = {0.f, 0.f, 0.f, 0.f};
#pragma unroll
            for (int s = 0; s < 2; ++s)
                c = __builtin_amdgcn_mfma_f32_16x16x32_bf16(
                    *(const bf8v*)&Ks[qg * 32 + mt * 16 + l15][s * 32 + l4 * 8],
                    bQ[qg][s], c, 0, 0, 0);
#pragma unroll
            for (int r = 0; r < 4; ++r)
                relHs[mt * 16 + l4 * 4 + r][qg * 64 + 16 * w + l15] =
                    (short)f2bf(c[r]);
        }

    f4v O[2][4];
#pragma unroll
    for (int qg = 0; qg < 2; ++qg)
#pragma unroll
        for (int nt = 0; nt < 4; ++nt) {
            O[qg][nt][0] = 0.f; O[qg][nt][1] = 0.f;
            O[qg][nt][2] = 0.f; O[qg][nt][3] = 0.f;
        }
    float ls[2] = {0.f, 0.f};

    const int xsel = ((lane >> 4) & 1) * 32 + l15;
    const bool lo32 = (lane < 32);

    for (int it = 0; it < 16; ++it) {
        __syncthreads();
        *(bf8v*)&Ks[sx][sck] = kpf[0];
        *(bf8v*)&Ks[sx][sck + 8] = kpf[1];
        *(bf8v*)&Ks[sx + 64][sck] = kpf[2];
        *(bf8v*)&Ks[sx + 64][sck + 8] = kpf[3];
        *(bf8v*)&Vt[sx][scv] = vpf[0];
        *(bf8v*)&Vt[sx][scv + 8] = vpf[1];
        *(bf8v*)&Vt[sx][scv + 16] = vpf[2];
        *(bf8v*)&Vt[sx][scv + 24] = vpf[3];
        {
            const int itn = (it < 15) ? it + 1 : 15;
            const short* kp = kptr + (size_t)itn * 128 * 64;
            const short* vp = vptr + itn * 128;
            kpf[0] = *(const bf8v*)kp;
            kpf[1] = *(const bf8v*)(kp + 8);
            kpf[2] = *(const bf8v*)(kp + 64 * 64);
            kpf[3] = *(const bf8v*)(kp + 64 * 64 + 8);
            vpf[0] = *(const bf8v*)vp;
            vpf[1] = *(const bf8v*)(vp + 8);
            vpf[2] = *(const bf8v*)(vp + 16);
            vpf[3] = *(const bf8v*)(vp + 24);
        }
        __syncthreads();

#pragma unroll
        for (int half = 0; half < 2; ++half) {
            // S^T: A-frags from Ks reused across both q-groups
            f4v acc[2][4];
#pragma unroll
            for (int qg = 0; qg < 2; ++qg)
#pragma unroll
                for (int nt = 0; nt < 4; ++nt) {
                    acc[qg][nt][0] = 0.f; acc[qg][nt][1] = 0.f;
                    acc[qg][nt][2] = 0.f; acc[qg][nt][3] = 0.f;
                }
#pragma unroll
            for (int s = 0; s < 2; ++s) {
                bf8v kf[4];
#pragma unroll
                for (int nt = 0; nt < 4; ++nt)
                    kf[nt] = *(const bf8v*)&Ks[half * 64 + nt * 16 + l15]
                                              [s * 32 + l4 * 8];
#pragma unroll
                for (int nt = 0; nt < 4; ++nt)
#pragma unroll
                    for (int qg = 0; qg < 2; ++qg)
                        acc[qg][nt] = __builtin_amdgcn_mfma_f32_16x16x32_bf16(
                            kf[nt], bQ[qg][s], acc[qg][nt], 0, 0, 0);
            }

            // softmax terms (no max): e = exp2(SC*acc + rw + rh)
            unsigned pk[2][4][2];
#pragma unroll
            for (int qg = 0; qg < 2; ++qg) {
                const float rh = bf2f((unsigned short)
                    relHs[2 * it + half][qg * 64 + 16 * w + l15]);
                float sub = 0.f;
#pragma unroll
                for (int nt = 0; nt < 4; ++nt) {
                    const unsigned u0 = rwp[qg][nt].x;
                    const unsigned u1 = rwp[qg][nt].y;
                    const float b0 = __uint_as_float(u0 << 16) + rh;
                    const float b1 = __uint_as_float(u0 & 0xffff0000u) + rh;
                    const float b2 = __uint_as_float(u1 << 16) + rh;
                    const float b3 = __uint_as_float(u1 & 0xffff0000u) + rh;
                    const float e0 =
                        __builtin_amdgcn_exp2f(fmaf(acc[qg][nt][0], SC, b0));
                    const float e1 =
                        __builtin_amdgcn_exp2f(fmaf(acc[qg][nt][1], SC, b1));
                    const float e2 =
                        __builtin_amdgcn_exp2f(fmaf(acc[qg][nt][2], SC, b2));
                    const float e3 =
                        __builtin_amdgcn_exp2f(fmaf(acc[qg][nt][3], SC, b3));
                    sub += (e0 + e1) + (e2 + e3);
                    pk[qg][nt][0] = pkbf(e1, e0);
                    pk[qg][nt][1] = pkbf(e3, e2);
                }
                ls[qg] += sub;
            }

            // C->A quad-permute transform per q-group
            bf8v aP[2][2];
#pragma unroll
            for (int qg = 0; qg < 2; ++qg)
#pragma unroll
                for (int s = 0; s < 2; ++s) {
                    const int x0 = __shfl((int)pk[qg][2 * s][0], xsel);
                    const int y0 = __shfl((int)pk[qg][2 * s + 1][0], xsel);
                    const int x1 = __shfl((int)pk[qg][2 * s][1], xsel);
                    const int y1 = __shfl((int)pk[qg][2 * s + 1][1], xsel);
                    const int x2 = __shfl((int)pk[qg][2 * s][0], xsel + 16);
                    const int y2 = __shfl((int)pk[qg][2 * s + 1][0], xsel + 16);
                    const int x3 = __shfl((int)pk[qg][2 * s][1], xsel + 16);
                    const int y3 = __shfl((int)pk[qg][2 * s + 1][1], xsel + 16);
                    int4 av;
                    av.x = lo32 ? x0 : y0;
                    av.y = lo32 ? x1 : y1;
                    av.z = lo32 ? x2 : y2;
                    av.w = lo32 ? x3 : y3;
                    union { int4 i; bf8v v; } u; u.i = av;
                    aP[qg][s] = u.v;
                }

            // O += P V : B-frags from Vt reused across both q-groups
#pragma unroll
            for (int s = 0; s < 2; ++s)
#pragma unroll
                for (int nt = 0; nt < 4; ++nt) {
                    bf8v vf = *(const bf8v*)&Vt[nt * 16 + l15]
                                               [half * 64 + s * 32 + l4 * 8];
#pragma unroll
                    for (int qg = 0; qg < 2; ++qg)
                        O[qg][nt] = __builtin_amdgcn_mfma_f32_16x16x32_bf16(
                            aP[qg][s], vf, O[qg][nt], 0, 0, 0);
                }
        }
    }

    // epilogue: write unnormalized partial O (bf16) + per-row l (fp32)
#pragma unroll
    for (int qg = 0; qg < 2; ++qg) {
        float l = ls[qg];
        l += __shfl_xor(l, 16);
        l += __shfl_xor(l, 32);
        if (l4 == 0)
            lpart[(size_t)(z * NHEADS + head) * NTOK + row0 + qg * 64 +
                  16 * w + l15] = l;
#pragma unroll
        for (int r = 0; r < 4; ++r) {
            const int row = row0 + qg * 64 + 16 * w + l4 * 4 + r;
#pragma unroll
            for (int nt = 0; nt < 4; ++nt)
                Opart[((size_t)z * NTOK + row) * 768 + head * 64 + nt * 16 +
                      l15] = (short)f2bf(O[qg][nt][r]);
        }
    }
}

// ---------------------------------------------------------------------------
// combine: aob[tok][c] = (O0 + O1) / (l0 + l1)   (bf16 out)
// ---------------------------------------------------------------------------
__global__ __launch_bounds__(256) void combine_kernel(
    const short* __restrict__ Opart, const float* __restrict__ lpart,
    short* __restrict__ aob)
{
    const size_t idx = ((size_t)blockIdx.x * 256 + threadIdx.x) * 8;
    const int tok = (int)(idx / 768);
    const int c = (int)(idx - (size_t)tok * 768);
    const int h = c >> 6;
    const float l = lpart[(size_t)h * NTOK + tok] +
                    lpart[(size_t)(NHEADS + h) * NTOK + tok];
    const float linv = 1.0f / l;
    bf8v a = *(const bf8v*)(Opart + idx);
    bf8v b = *(const bf8v*)(Opart + (size_t)NTOK * 768 + idx);
    bf8v o;
#pragma unroll
    for (int i = 0; i < 8; ++i)
        o[i] = (short)f2bf((bf2f((unsigned short)a[i]) +
                            bf2f((unsigned short)b[i])) * linv);
    *(bf8v*)(aob + idx) = o;
}

// ---------------------------------------------------------------------------
// proj GEMM (MFMA bf16): out[m][n] = aob[m][k] @ pwT[n][k]^T + bias[n] (fp32)
// ---------------------------------------------------------------------------
__global__ __launch_bounds__(256) void proj_mfma_kernel(
    const short* __restrict__ aoh, const short* __restrict__ pwT,
    const float* __restrict__ bias, float* __restrict__ out)
{
    __shared__ __align__(16) short As[128 * 32];
    __shared__ __align__(16) short Bs[128 * 32];
    const int t = threadIdx.x;
    const int w = t >> 6, lane = t & 63;
    const int l15 = lane & 15, l4 = lane >> 4;
    const int wr = w >> 1, wc = w & 1;
    const int row0 = blockIdx.y * 128, col0 = blockIdx.x * 128;
    const int ldr = lane >> 2;
    const int ldk = (lane & 3) * 8;

    f4v acc[4][4] = {};
    const short* aBase = aoh + (size_t)(row0 + w * 32 + ldr) * 768 + ldk;
    const short* bBase = pwT + (size_t)(col0 + w * 32 + ldr) * 768 + ldk;

    for (int kk = 0; kk < 768; kk += 32) {
        __syncthreads();
#pragma unroll
        for (int c = 0; c < 2; ++c) {
            gload_lds16(aBase + (size_t)c * 16 * 768 + kk,
                        &As[(w * 32 + c * 16) * 32]);
            gload_lds16(bBase + (size_t)c * 16 * 768 + kk,
                        &Bs[(w * 32 + c * 16) * 32]);
        }
        __syncthreads();
        bf8v af[4], bg[4];
#pragma unroll
        for (int i = 0; i < 4; ++i) {
            af[i] = *(const bf8v*)&As[(wr * 64 + 16 * i + l15) * 32 + l4 * 8];
            bg[i] = *(const bf8v*)&Bs[(wc * 64 + 16 * i + l15) * 32 + l4 * 8];
        }
#pragma unroll
        for (int i = 0; i < 4; ++i)
#pragma unroll
            for (int j = 0; j < 4; ++j)
                acc[i][j] = __builtin_amdgcn_mfma_f32_16x16x32_bf16(
                    af[i], bg[j], acc[i][j], 0, 0, 0);
    }

#pragma unroll
    for (int j = 0; j < 4; ++j) {
        const int n = col0 + wc * 64 + 16 * j + l15;
        const float bv = bias[n];
#pragma unroll
        for (int i = 0; i < 4; ++i) {
            const int m = row0 + wr * 64 + 16 * i + l4 * 4;
#pragma unroll
            for (int r = 0; r < 4; ++r)
                out[(size_t)(m + r) * 768 + n] = acc[i][j][r] + bv;
        }
    }
}

// ---------------------------------------------------------------------------
extern "C" void kernel_launch(void* const* d_in, const int* in_sizes, int n_in,
                              void* d_out, int out_size, void* d_ws,
                              size_t ws_size, hipStream_t stream)
{
    (void)in_sizes; (void)n_in; (void)out_size; (void)ws_size;
    const float* x    = (const float*)d_in[0];
    const float* qkvw = (const float*)d_in[1];
    const float* qkvb = (const float*)d_in[2];
    const float* pw   = (const float*)d_in[3];
    const float* pb   = (const float*)d_in[4];
    const float* rph  = (const float*)d_in[5];
    const float* rpw  = (const float*)d_in[6];
    float* out = (float*)d_out;

    const size_t S = (size_t)NHEADS * NTOK * 64;  // 3,145,728 (= 4096*768)
    short* rWb  = (short*)d_ws;          // S bf16 relW (LOG2E-scaled)
    short* qbh  = rWb + S;               // S bf16   q  [h][tok][d]
    short* kbh  = qbh + S;               // S bf16   k  [h][tok][d]
    short* vbT  = kbh + S;               // S bf16   v^T [h][d][tok]
    short* xh   = vbT + S;               // S bf16   x  [tok][c]
    short* aob  = xh + S;                // S bf16   attn out [tok][c]
    short* wqkvT = aob + S;              // 2304*768 bf16
    short* pwT  = wqkvT + (size_t)2304 * 768;  // 768*768 bf16
    short* rpwb = pwT + (size_t)768 * 768;     // 128*64 bf16 rel_pos_w
    short* Opart = rpwb + (size_t)128 * 64;    // 2*S bf16 partial O
    float* lpart = (float*)(Opart + 2 * S);    // 2*12*4096 fp32 partial l
    // total ~55.6 MB

    cvt_kernel<<<dim3(1536), 256, 0, stream>>>(x, xh);
    tcvt_kernel<<<dim3(36, 12), 256, 0, stream>>>(qkvw, wqkvT, 768, 2304);
    tcvt_kernel<<<dim3(12, 12), 256, 0, stream>>>(pw, pwT, 768, 768);
    cvt_rpw_kernel<<<dim3(32), 256, 0, stream>>>(rpw, rpwb);
    qkv_mfma_kernel<<<dim3(18, 32), 256, 0, stream>>>(xh, wqkvT, qkvb,
                                                      qbh, kbh, vbT);
    relu_kernel<<<dim3(NHEADS, 64), 256, 0, stream>>>(qbh, rpwb, rWb);
    flash_mfma_kernel<<<dim3(32, NHEADS, 2), 256, 0, stream>>>(
        qbh, kbh, vbT, rWb, rph, Opart, lpart);
    combine_kernel<<<dim3(1536), 256, 0, stream>>>(Opart, lpart, aob);
    proj_mfma_kernel<<<dim3(6, 32), 256, 0, stream>>>(aob, pwT, pb, out);
}

// Round 8
// 274.507 us; speedup vs baseline: 1.4504x; 1.4504x over previous
//
#include <hip/hip_runtime.h>
#include <math.h>

// Problem constants: B=1, H=W=64 (N=4096), C=768, 12 heads x hd=64.
#define NHEADS 12
#define NTOK 4096
#define LOG2E 1.44269504f

typedef __attribute__((ext_vector_type(8))) short bf8v;   // 8 x bf16 (4 VGPR)
typedef __attribute__((ext_vector_type(4))) float f4v;    // MFMA C/D frag

__device__ __forceinline__ unsigned short f2bf(float f) {
  unsigned int u = __float_as_uint(f);
  u += 0x7fffu + ((u >> 16) & 1u);   // RNE
  return (unsigned short)(u >> 16);
}
__device__ __forceinline__ float bf2f(unsigned short h) {
  return __uint_as_float(((unsigned int)h) << 16);
}
__device__ __forceinline__ bf8v pack8(float4 a, float4 b) {
  bf8v v;
  v[0] = (short)f2bf(a.x); v[1] = (short)f2bf(a.y);
  v[2] = (short)f2bf(a.z); v[3] = (short)f2bf(a.w);
  v[4] = (short)f2bf(b.x); v[5] = (short)f2bf(b.y);
  v[6] = (short)f2bf(b.z); v[7] = (short)f2bf(b.w);
  return v;
}
// pack two f32 (round via +0x8000) into (hi|lo) bf16 pair
__device__ __forceinline__ unsigned pkbf(float hi, float lo) {
  return __builtin_amdgcn_perm(__float_as_uint(hi) + 0x8000u,
                               __float_as_uint(lo) + 0x8000u, 0x07060302u);
}

// ---------------------------------------------------------------------------
// cvt: fp32 -> bf16 elementwise (x), 8 elems/thread
// ---------------------------------------------------------------------------
__global__ __launch_bounds__(256) void cvt_kernel(
    const float* __restrict__ in, short* __restrict__ out)
{
    const size_t i = ((size_t)blockIdx.x * 256 + threadIdx.x) * 8;
    float4 a = *(const float4*)(in + i);
    float4 b = *(const float4*)(in + i + 4);
    *(bf8v*)(out + i) = pack8(a, b);
}

// ---------------------------------------------------------------------------
// cvt_rpw: rel_pos_w fp32 [127][64] -> bf16 [128][64] (row 127 zeroed)
// ---------------------------------------------------------------------------
__global__ __launch_bounds__(256) void cvt_rpw_kernel(
    const float* __restrict__ in, short* __restrict__ out)
{
    const int idx = blockIdx.x * 256 + threadIdx.x;   // grid 32 -> 8192
    const float v = (idx < 127 * 64) ? in[idx] : 0.f;
    out[idx] = (short)f2bf(v);
}

// ---------------------------------------------------------------------------
// tcvt: fp32 in[R][C] -> bf16 out[C][R] (64x64 LDS tiles)
// ---------------------------------------------------------------------------
__global__ __launch_bounds__(256) void tcvt_kernel(
    const float* __restrict__ in, short* __restrict__ out, int R, int C)
{
    __shared__ float Ts[64][65];
    const int bc = blockIdx.x * 64, br = blockIdx.y * 64, t = threadIdx.x;
    {
        const int r = t >> 2, c0 = (t & 3) * 16;
        const float* src = in + (size_t)(br + r) * C + bc + c0;
#pragma unroll
        for (int i = 0; i < 4; ++i) {
            float4 a = *(const float4*)(src + 4 * i);
            Ts[r][c0 + 4 * i + 0] = a.x;
            Ts[r][c0 + 4 * i + 1] = a.y;
            Ts[r][c0 + 4 * i + 2] = a.z;
            Ts[r][c0 + 4 * i + 3] = a.w;
        }
    }
    __syncthreads();
    const int c = t >> 2, r0 = (t & 3) * 16;
    short* dst = out + (size_t)(bc + c) * R + br + r0;
#pragma unroll
    for (int p = 0; p < 2; ++p) {
        bf8v v;
#pragma unroll
        for (int i = 0; i < 8; ++i) v[i] = (short)f2bf(Ts[r0 + p * 8 + i][c]);
        *(bf8v*)(dst + p * 8) = v;
    }
}

// ---------------------------------------------------------------------------
// QKV GEMM (MFMA bf16): C[m][n] = xh[m][k] @ wT[n][k]^T + bias[n]
// ---------------------------------------------------------------------------
__device__ __forceinline__ void gload_lds16(const void* g, void* l) {
  __builtin_amdgcn_global_load_lds(
      (const __attribute__((address_space(1))) void*)g,
      (__attribute__((address_space(3))) void*)l, 16, 0, 0);
}

__global__ __launch_bounds__(256) void qkv_mfma_kernel(
    const short* __restrict__ xh, const short* __restrict__ wT,
    const float* __restrict__ bias, short* __restrict__ qbh,
    short* __restrict__ kbh, short* __restrict__ vbT)
{
    __shared__ __align__(16) short As[128 * 32];
    __shared__ __align__(16) short Bs[128 * 32];
    const int t = threadIdx.x;
    const int w = t >> 6, lane = t & 63;
    const int l15 = lane & 15, l4 = lane >> 4;
    const int wr = w >> 1, wc = w & 1;
    const int row0 = blockIdx.y * 128, col0 = blockIdx.x * 128;
    const int ldr = lane >> 2;
    const int ldk = (lane & 3) * 8;

    f4v acc[4][4] = {};
    const short* aBase = xh + (size_t)(row0 + w * 32 + ldr) * 768 + ldk;
    const short* bBase = wT + (size_t)(col0 + w * 32 + ldr) * 768 + ldk;

    for (int kk = 0; kk < 768; kk += 32) {
        __syncthreads();
#pragma unroll
        for (int c = 0; c < 2; ++c) {
            gload_lds16(aBase + (size_t)c * 16 * 768 + kk,
                        &As[(w * 32 + c * 16) * 32]);
            gload_lds16(bBase + (size_t)c * 16 * 768 + kk,
                        &Bs[(w * 32 + c * 16) * 32]);
        }
        __syncthreads();
        bf8v af[4], bg[4];
#pragma unroll
        for (int i = 0; i < 4; ++i) {
            af[i] = *(const bf8v*)&As[(wr * 64 + 16 * i + l15) * 32 + l4 * 8];
            bg[i] = *(const bf8v*)&Bs[(wc * 64 + 16 * i + l15) * 32 + l4 * 8];
        }
#pragma unroll
        for (int i = 0; i < 4; ++i)
#pragma unroll
            for (int j = 0; j < 4; ++j)
                acc[i][j] = __builtin_amdgcn_mfma_f32_16x16x32_bf16(
                    af[i], bg[j], acc[i][j], 0, 0, 0);
    }

#pragma unroll
    for (int j = 0; j < 4; ++j) {
        const int n = col0 + wc * 64 + 16 * j + l15;
        const int s = n / 768;            // block-uniform (768 = 6*128)
        const int rm = n - s * 768;
        const int h = rm >> 6, d = rm & 63;
        const float bv = bias[n];
        if (s == 2) {
            short* vdst = vbT + (size_t)(h * 64 + d) * NTOK;
#pragma unroll
            for (int i = 0; i < 4; ++i) {
                const int m = row0 + wr * 64 + 16 * i + l4 * 4;
                short4 pv;
                pv.x = (short)f2bf(acc[i][j][0] + bv);
                pv.y = (short)f2bf(acc[i][j][1] + bv);
                pv.z = (short)f2bf(acc[i][j][2] + bv);
                pv.w = (short)f2bf(acc[i][j][3] + bv);
                *(short4*)(vdst + m) = pv;
            }
        } else {
            short* dst = (s == 0) ? qbh : kbh;
#pragma unroll
            for (int i = 0; i < 4; ++i) {
                const int m = row0 + wr * 64 + 16 * i + l4 * 4;
#pragma unroll
                for (int r = 0; r < 4; ++r)
                    dst[((size_t)h * NTOK + m + r) * 64 + d] =
                        (short)f2bf(acc[i][j][r] + bv);
            }
        }
    }
}

// ---------------------------------------------------------------------------
// relu: U[j][qw] = sum_d rpwb[j][d] * Q[h][qh*64+qw][d]  (MFMA, per (h,qh))
// then rW[h][qh*64+qw][kw] = LOG2E * U[qw+63-kw][qw]   (LDS gather, fp32)
// ---------------------------------------------------------------------------
__global__ __launch_bounds__(256) void relu_kernel(
    const short* __restrict__ qbh, const short* __restrict__ rpwb,
    float* __restrict__ rW)
{
    __shared__ float Us[128][65];
    const int h = blockIdx.x, qh = blockIdx.y;
    const int t = threadIdx.x, w = t >> 6, lane = t & 63;
    const int l15 = lane & 15, l4 = lane >> 4;
    const size_t hB = (size_t)h * NTOK * 64;

    bf8v bq[4][2];
#pragma unroll
    for (int nt = 0; nt < 4; ++nt) {
        const short* qs = qbh + hB + (size_t)(qh * 64 + nt * 16 + l15) * 64;
#pragma unroll
        for (int s = 0; s < 2; ++s)
            bq[nt][s] = *(const bf8v*)(qs + s * 32 + l4 * 8);
    }
    bf8v aw[2][2];
#pragma unroll
    for (int mi = 0; mi < 2; ++mi) {
        const short* as = rpwb + (size_t)((w * 2 + mi) * 16 + l15) * 64;
#pragma unroll
        for (int s = 0; s < 2; ++s)
            aw[mi][s] = *(const bf8v*)(as + s * 32 + l4 * 8);
    }
    f4v U[2][4] = {};
#pragma unroll
    for (int mi = 0; mi < 2; ++mi)
#pragma unroll
        for (int nt = 0; nt < 4; ++nt)
#pragma unroll
            for (int s = 0; s < 2; ++s)
                U[mi][nt] = __builtin_amdgcn_mfma_f32_16x16x32_bf16(
                    aw[mi][s], bq[nt][s], U[mi][nt], 0, 0, 0);
#pragma unroll
    for (int mi = 0; mi < 2; ++mi)
#pragma unroll
        for (int nt = 0; nt < 4; ++nt)
#pragma unroll
            for (int r = 0; r < 4; ++r)
                Us[(w * 2 + mi) * 16 + l4 * 4 + r][nt * 16 + l15] =
                    U[mi][nt][r];
    __syncthreads();
    const int kw = t & 63, q0 = t >> 6;
#pragma unroll
    for (int i = 0; i < 16; ++i) {
        const int q = q0 * 16 + i;
        rW[hB + (size_t)(qh * 64 + q) * 64 + kw] =
            Us[q + 63 - kw][q] * LOG2E;
    }
}

// ---------------------------------------------------------------------------
// Flash attention, S^T formulation, TK=128 (2 sub-tiles/iter), no-max softmax.
// Block = (q-tile 64, head), 4 waves. Each lane owns ONE softmax row (q =
// 16w + lane&15); l is a deferred plain sum (no running max: |logit| << 88,
// and dropping the max subtraction is an exact common rescale of P and l).
// ---------------------------------------------------------------------------
__global__ __launch_bounds__(256, 3) void flash_mfma_kernel(
    const short* __restrict__ qbh, const short* __restrict__ kbh,
    const short* __restrict__ vbT, const float* __restrict__ rW,
    const float* __restrict__ rph, short* __restrict__ aob)
{
    __shared__ __align__(16) short Ks[128][68];   // [tok][d], pad 4 (uniform banks)
    __shared__ __align__(16) short Vt[64][132];   // [d][tok], pad 4
    __shared__ float relHs[64][65];               // [kh][q-local] (log2e-scaled)

    const int t = threadIdx.x;
    const int qt = blockIdx.x, head = blockIdx.y;
    const int row0 = qt * 64;
    const int lane = t & 63, w = t >> 6;
    const int l15 = lane & 15, l4 = lane >> 4;
    const size_t hB = (size_t)head * NTOK * 64;
    const float SC = 0.125f * LOG2E;

    // Q as B-fragments (n = q-row = 16w + l15), k = s*32 + l4*8 + j
    bf8v bQ[2];
    {
        const short* qsrc = qbh + hB + (size_t)(row0 + 16 * w + l15) * 64;
#pragma unroll
        for (int s = 0; s < 2; ++s)
            bQ[s] = *(const bf8v*)(qsrc + s * 32 + l4 * 8);
    }
    // relW preload (LOG2E-scaled): element (q=l15, kw=16nt+4l4+r)
    float rw[4][4];
#pragma unroll
    for (int nt = 0; nt < 4; ++nt)
#pragma unroll
        for (int r = 0; r < 4; ++r)
            rw[nt][r] = rW[hB + (size_t)(row0 + 16 * w + l15) * 64 +
                           nt * 16 + l4 * 4 + r];

    // stage reversed rph slice (x LOG2E) into Ks rows 0..63 for relH GEMM
    {
        const int rr = t >> 2, d0 = (t & 3) * 16;
        const float* src = rph + (size_t)(qt + 63 - rr) * 64 + d0;
        float4 a0 = *(const float4*)(src);
        float4 a1 = *(const float4*)(src + 4);
        float4 a2 = *(const float4*)(src + 8);
        float4 a3 = *(const float4*)(src + 12);
        a0.x *= LOG2E; a0.y *= LOG2E; a0.z *= LOG2E; a0.w *= LOG2E;
        a1.x *= LOG2E; a1.y *= LOG2E; a1.z *= LOG2E; a1.w *= LOG2E;
        a2.x *= LOG2E; a2.y *= LOG2E; a2.z *= LOG2E; a2.w *= LOG2E;
        a3.x *= LOG2E; a3.y *= LOG2E; a3.z *= LOG2E; a3.w *= LOG2E;
        *(bf8v*)&Ks[rr][d0] = pack8(a0, a1);
        *(bf8v*)&Ks[rr][d0 + 8] = pack8(a2, a3);
    }
    // prefetch K/V tile 0 into registers (TK=128: 2 K rows + 64B of V^T each)
    const int sx = t >> 2;            // K token row (and V d-row)
    const int sck = (t & 3) * 16;     // K d-offset (shorts)
    const int scv = (t & 3) * 32;     // V token-offset (shorts)
    const short* kptr = kbh + hB + (size_t)sx * 64 + sck;
    const short* vptr = vbT + ((size_t)head * 64 + sx) * NTOK + scv;
    bf8v kpf[4], vpf[4];
    kpf[0] = *(const bf8v*)(kptr);
    kpf[1] = *(const bf8v*)(kptr + 8);
    kpf[2] = *(const bf8v*)(kptr + 64 * 64);
    kpf[3] = *(const bf8v*)(kptr + 64 * 64 + 8);
    vpf[0] = *(const bf8v*)(vptr);
    vpf[1] = *(const bf8v*)(vptr + 8);
    vpf[2] = *(const bf8v*)(vptr + 16);
    vpf[3] = *(const bf8v*)(vptr + 24);

    __syncthreads();
    // relHs = rph_rev · Q^T  (m = kh, n = q-local)
#pragma unroll
    for (int nt = 0; nt < 4; ++nt) {
        f4v c = {0.f, 0.f, 0.f, 0.f};
#pragma unroll
        for (int s = 0; s < 2; ++s)
            c = __builtin_amdgcn_mfma_f32_16x16x32_bf16(
                *(const bf8v*)&Ks[nt * 16 + l15][s * 32 + l4 * 8], bQ[s], c,
                0, 0, 0);
#pragma unroll
        for (int r = 0; r < 4; ++r)
            relHs[nt * 16 + l4 * 4 + r][16 * w + l15] = c[r];
    }

    f4v O[4] = {{0.f, 0.f, 0.f, 0.f}, {0.f, 0.f, 0.f, 0.f},
                {0.f, 0.f, 0.f, 0.f}, {0.f, 0.f, 0.f, 0.f}};
    float lsum = 0.f;

    const int xsel = ((lane >> 4) & 1) * 32 + l15;      // transform src lane
    const bool lo32 = (lane < 32);

    for (int it = 0; it < 32; ++it) {
        __syncthreads();
        *(bf8v*)&Ks[sx][sck] = kpf[0];
        *(bf8v*)&Ks[sx][sck + 8] = kpf[1];
        *(bf8v*)&Ks[sx + 64][sck] = kpf[2];
        *(bf8v*)&Ks[sx + 64][sck + 8] = kpf[3];
        *(bf8v*)&Vt[sx][scv] = vpf[0];
        *(bf8v*)&Vt[sx][scv + 8] = vpf[1];
        *(bf8v*)&Vt[sx][scv + 16] = vpf[2];
        *(bf8v*)&Vt[sx][scv + 24] = vpf[3];
        {
            const int itn = (it < 31) ? it + 1 : 31;
            const short* kp = kptr + (size_t)itn * 128 * 64;
            const short* vp = vptr + itn * 128;
            kpf[0] = *(const bf8v*)kp;
            kpf[1] = *(const bf8v*)(kp + 8);
            kpf[2] = *(const bf8v*)(kp + 64 * 64);
            kpf[3] = *(const bf8v*)(kp + 64 * 64 + 8);
            vpf[0] = *(const bf8v*)vp;
            vpf[1] = *(const bf8v*)(vp + 8);
            vpf[2] = *(const bf8v*)(vp + 16);
            vpf[3] = *(const bf8v*)(vp + 24);
        }
        __syncthreads();

        // S^T for both sub-tiles (independent chains)
        f4v accA[4] = {{0.f, 0.f, 0.f, 0.f}, {0.f, 0.f, 0.f, 0.f},
                       {0.f, 0.f, 0.f, 0.f}, {0.f, 0.f, 0.f, 0.f}};
        f4v accB[4] = {{0.f, 0.f, 0.f, 0.f}, {0.f, 0.f, 0.f, 0.f},
                       {0.f, 0.f, 0.f, 0.f}, {0.f, 0.f, 0.f, 0.f}};
#pragma unroll
        for (int s = 0; s < 2; ++s)
#pragma unroll
            for (int nt = 0; nt < 4; ++nt) {
                accA[nt] = __builtin_amdgcn_mfma_f32_16x16x32_bf16(
                    *(const bf8v*)&Ks[nt * 16 + l15][s * 32 + l4 * 8], bQ[s],
                    accA[nt], 0, 0, 0);
                accB[nt] = __builtin_amdgcn_mfma_f32_16x16x32_bf16(
                    *(const bf8v*)&Ks[64 + nt * 16 + l15][s * 32 + l4 * 8],
                    bQ[s], accB[nt], 0, 0, 0);
            }

        const float rhA = relHs[2 * it][16 * w + l15];
        const float rhB = relHs[2 * it + 1][16 * w + l15];

        // e = exp2(SC*acc + (rw + rh)); no max subtraction (exact rescale)
        float eA[4][4], eB[4][4];
#pragma unroll
        for (int nt = 0; nt < 4; ++nt)
#pragma unroll
            for (int r = 0; r < 4; ++r) {
                eA[nt][r] = __builtin_amdgcn_exp2f(
                    fmaf(accA[nt][r], SC, rw[nt][r] + rhA));
                eB[nt][r] = __builtin_amdgcn_exp2f(
                    fmaf(accB[nt][r], SC, rw[nt][r] + rhB));
            }
        // deferred l: per-lane partial sum (reduced once in epilogue)
        {
            float sA = ((eA[0][0] + eA[0][1]) + (eA[0][2] + eA[0][3])) +
                       ((eA[1][0] + eA[1][1]) + (eA[1][2] + eA[1][3])) +
                       ((eA[2][0] + eA[2][1]) + (eA[2][2] + eA[2][3])) +
                       ((eA[3][0] + eA[3][1]) + (eA[3][2] + eA[3][3]));
            float sB = ((eB[0][0] + eB[0][1]) + (eB[0][2] + eB[0][3])) +
                       ((eB[1][0] + eB[1][1]) + (eB[1][2] + eB[1][3])) +
                       ((eB[2][0] + eB[2][1]) + (eB[2][2] + eB[2][3])) +
                       ((eB[3][0] + eB[3][1]) + (eB[3][2] + eB[3][3]));
            lsum += sA + sB;
        }

        // pack P, C->A quad-permute transform, PV accumulate per sub-tile
#pragma unroll
        for (int half = 0; half < 2; ++half) {
            float (*e)[4] = half ? eB : eA;
            unsigned pk[4][2];
#pragma unroll
            for (int nt = 0; nt < 4; ++nt) {
                pk[nt][0] = pkbf(e[nt][1], e[nt][0]);
                pk[nt][1] = pkbf(e[nt][3], e[nt][2]);
            }
            bf8v aP[2];
#pragma unroll
            for (int s = 0; s < 2; ++s) {
                const int x0 = __shfl((int)pk[2 * s][0], xsel);
                const int y0 = __shfl((int)pk[2 * s + 1][0], xsel);
                const int x1 = __shfl((int)pk[2 * s][1], xsel);
                const int y1 = __shfl((int)pk[2 * s + 1][1], xsel);
                const int x2 = __shfl((int)pk[2 * s][0], xsel + 16);
                const int y2 = __shfl((int)pk[2 * s + 1][0], xsel + 16);
                const int x3 = __shfl((int)pk[2 * s][1], xsel + 16);
                const int y3 = __shfl((int)pk[2 * s + 1][1], xsel + 16);
                int4 av;
                av.x = lo32 ? x0 : y0;
                av.y = lo32 ? x1 : y1;
                av.z = lo32 ? x2 : y2;
                av.w = lo32 ? x3 : y3;
                union { int4 i; bf8v v; } u; u.i = av;
                aP[s] = u.v;
            }
#pragma unroll
            for (int s = 0; s < 2; ++s)
#pragma unroll
                for (int nt = 0; nt < 4; ++nt)
                    O[nt] = __builtin_amdgcn_mfma_f32_16x16x32_bf16(
                        aP[s],
                        *(const bf8v*)&Vt[nt * 16 + l15]
                                         [half * 64 + s * 32 + l4 * 8],
                        O[nt], 0, 0, 0);
        }
    }

    // epilogue: reduce l across the 4 token-partitions, normalize, store
    lsum += __shfl_xor(lsum, 16);
    lsum += __shfl_xor(lsum, 32);
    const float linv = 1.0f / lsum;
    float li[4];
#pragma unroll
    for (int r = 0; r < 4; ++r) li[r] = __shfl(linv, 4 * l4 + r);
#pragma unroll
    for (int r = 0; r < 4; ++r) {
        const int row = row0 + 16 * w + l4 * 4 + r;
#pragma unroll
        for (int nt = 0; nt < 4; ++nt)
            aob[(size_t)row * 768 + head * 64 + nt * 16 + l15] =
                (short)f2bf(O[nt][r] * li[r]);
    }
}

// ---------------------------------------------------------------------------
// proj GEMM (MFMA bf16): out[m][n] = aob[m][k] @ pwT[n][k]^T + bias[n] (fp32)
// ---------------------------------------------------------------------------
__global__ __launch_bounds__(256) void proj_mfma_kernel(
    const short* __restrict__ aoh, const short* __restrict__ pwT,
    const float* __restrict__ bias, float* __restrict__ out)
{
    __shared__ __align__(16) short As[128 * 32];
    __shared__ __align__(16) short Bs[128 * 32];
    const int t = threadIdx.x;
    const int w = t >> 6, lane = t & 63;
    const int l15 = lane & 15, l4 = lane >> 4;
    const int wr = w >> 1, wc = w & 1;
    const int row0 = blockIdx.y * 128, col0 = blockIdx.x * 128;
    const int ldr = lane >> 2;
    const int ldk = (lane & 3) * 8;

    f4v acc[4][4] = {};
    const short* aBase = aoh + (size_t)(row0 + w * 32 + ldr) * 768 + ldk;
    const short* bBase = pwT + (size_t)(col0 + w * 32 + ldr) * 768 + ldk;

    for (int kk = 0; kk < 768; kk += 32) {
        __syncthreads();
#pragma unroll
        for (int c = 0; c < 2; ++c) {
            gload_lds16(aBase + (size_t)c * 16 * 768 + kk,
                        &As[(w * 32 + c * 16) * 32]);
            gload_lds16(bBase + (size_t)c * 16 * 768 + kk,
                        &Bs[(w * 32 + c * 16) * 32]);
        }
        __syncthreads();
        bf8v af[4], bg[4];
#pragma unroll
        for (int i = 0; i < 4; ++i) {
            af[i] = *(const bf8v*)&As[(wr * 64 + 16 * i + l15) * 32 + l4 * 8];
            bg[i] = *(const bf8v*)&Bs[(wc * 64 + 16 * i + l15) * 32 + l4 * 8];
        }
#pragma unroll
        for (int i = 0; i < 4; ++i)
#pragma unroll
            for (int j = 0; j < 4; ++j)
                acc[i][j] = __builtin_amdgcn_mfma_f32_16x16x32_bf16(
                    af[i], bg[j], acc[i][j], 0, 0, 0);
    }

#pragma unroll
    for (int j = 0; j < 4; ++j) {
        const int n = col0 + wc * 64 + 16 * j + l15;
        const float bv = bias[n];
#pragma unroll
        for (int i = 0; i < 4; ++i) {
            const int m = row0 + wr * 64 + 16 * i + l4 * 4;
#pragma unroll
            for (int r = 0; r < 4; ++r)
                out[(size_t)(m + r) * 768 + n] = acc[i][j][r] + bv;
        }
    }
}

// ---------------------------------------------------------------------------
extern "C" void kernel_launch(void* const* d_in, const int* in_sizes, int n_in,
                              void* d_out, int out_size, void* d_ws,
                              size_t ws_size, hipStream_t stream)
{
    (void)in_sizes; (void)n_in; (void)out_size; (void)ws_size;
    const float* x    = (const float*)d_in[0];
    const float* qkvw = (const float*)d_in[1];
    const float* qkvb = (const float*)d_in[2];
    const float* pw   = (const float*)d_in[3];
    const float* pb   = (const float*)d_in[4];
    const float* rph  = (const float*)d_in[5];
    const float* rpw  = (const float*)d_in[6];
    float* out = (float*)d_out;

    const size_t S = (size_t)NHEADS * NTOK * 64;  // 3,145,728 (= 4096*768)
    float* rW   = (float*)d_ws;          // S fp32 relW (LOG2E-scaled)
    short* qbh  = (short*)(rW + S);      // S bf16   q  [h][tok][d]
    short* kbh  = qbh + S;               // S bf16   k  [h][tok][d]
    short* vbT  = kbh + S;               // S bf16   v^T [h][d][tok]
    short* xh   = vbT + S;               // S bf16   x  [tok][c]
    short* aob  = xh + S;                // S bf16   attn out [tok][c]
    short* wqkvT = aob + S;              // 2304*768 bf16
    short* pwT  = wqkvT + (size_t)2304 * 768;  // 768*768 bf16
    short* rpwb = pwT + (size_t)768 * 768;     // 128*64 bf16 rel_pos_w
    // total ~48.8 MB

    cvt_kernel<<<dim3(1536), 256, 0, stream>>>(x, xh);
    tcvt_kernel<<<dim3(36, 12), 256, 0, stream>>>(qkvw, wqkvT, 768, 2304);
    tcvt_kernel<<<dim3(12, 12), 256, 0, stream>>>(pw, pwT, 768, 768);
    cvt_rpw_kernel<<<dim3(32), 256, 0, stream>>>(rpw, rpwb);
    qkv_mfma_kernel<<<dim3(18, 32), 256, 0, stream>>>(xh, wqkvT, qkvb,
                                                      qbh, kbh, vbT);
    relu_kernel<<<dim3(NHEADS, 64), 256, 0, stream>>>(qbh, rpwb, rW);
    flash_mfma_kernel<<<dim3(64, NHEADS), 256, 0, stream>>>(qbh, kbh, vbT, rW,
                                                            rph, aob);
    proj_mfma_kernel<<<dim3(6, 32), 256, 0, stream>>>(aob, pwT, pb, out);
}

// Round 9
// 247.172 us; speedup vs baseline: 1.6108x; 1.1106x over previous
//
#include <hip/hip_runtime.h>
#include <math.h>

// Problem constants: B=1, H=W=64 (N=4096), C=768, 12 heads x hd=64.
#define NHEADS 12
#define NTOK 4096
#define LOG2E 1.44269504f

typedef __attribute__((ext_vector_type(8))) short bf8v;   // 8 x bf16 (4 VGPR)
typedef __attribute__((ext_vector_type(4))) float f4v;    // MFMA C/D frag

#if __has_builtin(__builtin_amdgcn_permlane32_swap) && \
    __has_builtin(__builtin_amdgcn_permlane16_swap)
#define HAVE_PERMLANE_SWAP 1
#endif

__device__ __forceinline__ unsigned short f2bf(float f) {
  unsigned int u = __float_as_uint(f);
  u += 0x7fffu + ((u >> 16) & 1u);   // RNE
  return (unsigned short)(u >> 16);
}
__device__ __forceinline__ float bf2f(unsigned short h) {
  return __uint_as_float(((unsigned int)h) << 16);
}
__device__ __forceinline__ bf8v pack8(float4 a, float4 b) {
  bf8v v;
  v[0] = (short)f2bf(a.x); v[1] = (short)f2bf(a.y);
  v[2] = (short)f2bf(a.z); v[3] = (short)f2bf(a.w);
  v[4] = (short)f2bf(b.x); v[5] = (short)f2bf(b.y);
  v[6] = (short)f2bf(b.z); v[7] = (short)f2bf(b.w);
  return v;
}
// pack two f32 (round via +0x8000) into (hi|lo) bf16 pair
__device__ __forceinline__ unsigned pkbf(float hi, float lo) {
  return __builtin_amdgcn_perm(__float_as_uint(hi) + 0x8000u,
                               __float_as_uint(lo) + 0x8000u, 0x07060302u);
}

// ---------------------------------------------------------------------------
// cvt: fp32 -> bf16 elementwise (x), 8 elems/thread
// ---------------------------------------------------------------------------
__global__ __launch_bounds__(256) void cvt_kernel(
    const float* __restrict__ in, short* __restrict__ out)
{
    const size_t i = ((size_t)blockIdx.x * 256 + threadIdx.x) * 8;
    float4 a = *(const float4*)(in + i);
    float4 b = *(const float4*)(in + i + 4);
    *(bf8v*)(out + i) = pack8(a, b);
}

// ---------------------------------------------------------------------------
// cvt_rpw: rel_pos_w fp32 [127][64] -> bf16 [128][64] (row 127 zeroed)
// ---------------------------------------------------------------------------
__global__ __launch_bounds__(256) void cvt_rpw_kernel(
    const float* __restrict__ in, short* __restrict__ out)
{
    const int idx = blockIdx.x * 256 + threadIdx.x;   // grid 32 -> 8192
    const float v = (idx < 127 * 64) ? in[idx] : 0.f;
    out[idx] = (short)f2bf(v);
}

// ---------------------------------------------------------------------------
// tcvt: fp32 in[R][C] -> bf16 out[C][R] (64x64 LDS tiles)
// ---------------------------------------------------------------------------
__global__ __launch_bounds__(256) void tcvt_kernel(
    const float* __restrict__ in, short* __restrict__ out, int R, int C)
{
    __shared__ float Ts[64][65];
    const int bc = blockIdx.x * 64, br = blockIdx.y * 64, t = threadIdx.x;
    {
        const int r = t >> 2, c0 = (t & 3) * 16;
        const float* src = in + (size_t)(br + r) * C + bc + c0;
#pragma unroll
        for (int i = 0; i < 4; ++i) {
            float4 a = *(const float4*)(src + 4 * i);
            Ts[r][c0 + 4 * i + 0] = a.x;
            Ts[r][c0 + 4 * i + 1] = a.y;
            Ts[r][c0 + 4 * i + 2] = a.z;
            Ts[r][c0 + 4 * i + 3] = a.w;
        }
    }
    __syncthreads();
    const int c = t >> 2, r0 = (t & 3) * 16;
    short* dst = out + (size_t)(bc + c) * R + br + r0;
#pragma unroll
    for (int p = 0; p < 2; ++p) {
        bf8v v;
#pragma unroll
        for (int i = 0; i < 8; ++i) v[i] = (short)f2bf(Ts[r0 + p * 8 + i][c]);
        *(bf8v*)(dst + p * 8) = v;
    }
}

// ---------------------------------------------------------------------------
// QKV GEMM (MFMA bf16): C[m][n] = xh[m][k] @ wT[n][k]^T + bias[n]
// ---------------------------------------------------------------------------
__device__ __forceinline__ void gload_lds16(const void* g, void* l) {
  __builtin_amdgcn_global_load_lds(
      (const __attribute__((address_space(1))) void*)g,
      (__attribute__((address_space(3))) void*)l, 16, 0, 0);
}

__global__ __launch_bounds__(256) void qkv_mfma_kernel(
    const short* __restrict__ xh, const short* __restrict__ wT,
    const float* __restrict__ bias, short* __restrict__ qbh,
    short* __restrict__ kbh, short* __restrict__ vbT)
{
    __shared__ __align__(16) short As[128 * 32];
    __shared__ __align__(16) short Bs[128 * 32];
    const int t = threadIdx.x;
    const int w = t >> 6, lane = t & 63;
    const int l15 = lane & 15, l4 = lane >> 4;
    const int wr = w >> 1, wc = w & 1;
    const int row0 = blockIdx.y * 128, col0 = blockIdx.x * 128;
    const int ldr = lane >> 2;
    const int ldk = (lane & 3) * 8;

    f4v acc[4][4] = {};
    const short* aBase = xh + (size_t)(row0 + w * 32 + ldr) * 768 + ldk;
    const short* bBase = wT + (size_t)(col0 + w * 32 + ldr) * 768 + ldk;

    for (int kk = 0; kk < 768; kk += 32) {
        __syncthreads();
#pragma unroll
        for (int c = 0; c < 2; ++c) {
            gload_lds16(aBase + (size_t)c * 16 * 768 + kk,
                        &As[(w * 32 + c * 16) * 32]);
            gload_lds16(bBase + (size_t)c * 16 * 768 + kk,
                        &Bs[(w * 32 + c * 16) * 32]);
        }
        __syncthreads();
        bf8v af[4], bg[4];
#pragma unroll
        for (int i = 0; i < 4; ++i) {
            af[i] = *(const bf8v*)&As[(wr * 64 + 16 * i + l15) * 32 + l4 * 8];
            bg[i] = *(const bf8v*)&Bs[(wc * 64 + 16 * i + l15) * 32 + l4 * 8];
        }
#pragma unroll
        for (int i = 0; i < 4; ++i)
#pragma unroll
            for (int j = 0; j < 4; ++j)
                acc[i][j] = __builtin_amdgcn_mfma_f32_16x16x32_bf16(
                    af[i], bg[j], acc[i][j], 0, 0, 0);
    }

#pragma unroll
    for (int j = 0; j < 4; ++j) {
        const int n = col0 + wc * 64 + 16 * j + l15;
        const int s = n / 768;            // block-uniform (768 = 6*128)
        const int rm = n - s * 768;
        const int h = rm >> 6, d = rm & 63;
        const float bv = bias[n];
        if (s == 2) {
            short* vdst = vbT + (size_t)(h * 64 + d) * NTOK;
#pragma unroll
            for (int i = 0; i < 4; ++i) {
                const int m = row0 + wr * 64 + 16 * i + l4 * 4;
                short4 pv;
                pv.x = (short)f2bf(acc[i][j][0] + bv);
                pv.y = (short)f2bf(acc[i][j][1] + bv);
                pv.z = (short)f2bf(acc[i][j][2] + bv);
                pv.w = (short)f2bf(acc[i][j][3] + bv);
                *(short4*)(vdst + m) = pv;
            }
        } else {
            short* dst = (s == 0) ? qbh : kbh;
#pragma unroll
            for (int i = 0; i < 4; ++i) {
                const int m = row0 + wr * 64 + 16 * i + l4 * 4;
#pragma unroll
                for (int r = 0; r < 4; ++r)
                    dst[((size_t)h * NTOK + m + r) * 64 + d] =
                        (short)f2bf(acc[i][j][r] + bv);
            }
        }
    }
}

// ---------------------------------------------------------------------------
// relu: U[j][qw] = sum_d rpwb[j][d] * Q[h][qh*64+qw][d]  (MFMA, per (h,qh))
// then rW[h][qh*64+qw][kw] = LOG2E * U[qw+63-kw][qw]   (LDS gather, fp32)
// ---------------------------------------------------------------------------
__global__ __launch_bounds__(256) void relu_kernel(
    const short* __restrict__ qbh, const short* __restrict__ rpwb,
    float* __restrict__ rW)
{
    __shared__ float Us[128][65];
    const int h = blockIdx.x, qh = blockIdx.y;
    const int t = threadIdx.x, w = t >> 6, lane = t & 63;
    const int l15 = lane & 15, l4 = lane >> 4;
    const size_t hB = (size_t)h * NTOK * 64;

    bf8v bq[4][2];
#pragma unroll
    for (int nt = 0; nt < 4; ++nt) {
        const short* qs = qbh + hB + (size_t)(qh * 64 + nt * 16 + l15) * 64;
#pragma unroll
        for (int s = 0; s < 2; ++s)
            bq[nt][s] = *(const bf8v*)(qs + s * 32 + l4 * 8);
    }
    bf8v aw[2][2];
#pragma unroll
    for (int mi = 0; mi < 2; ++mi) {
        const short* as = rpwb + (size_t)((w * 2 + mi) * 16 + l15) * 64;
#pragma unroll
        for (int s = 0; s < 2; ++s)
            aw[mi][s] = *(const bf8v*)(as + s * 32 + l4 * 8);
    }
    f4v U[2][4] = {};
#pragma unroll
    for (int mi = 0; mi < 2; ++mi)
#pragma unroll
        for (int nt = 0; nt < 4; ++nt)
#pragma unroll
            for (int s = 0; s < 2; ++s)
                U[mi][nt] = __builtin_amdgcn_mfma_f32_16x16x32_bf16(
                    aw[mi][s], bq[nt][s], U[mi][nt], 0, 0, 0);
#pragma unroll
    for (int mi = 0; mi < 2; ++mi)
#pragma unroll
        for (int nt = 0; nt < 4; ++nt)
#pragma unroll
            for (int r = 0; r < 4; ++r)
                Us[(w * 2 + mi) * 16 + l4 * 4 + r][nt * 16 + l15] =
                    U[mi][nt][r];
    __syncthreads();
    const int kw = t & 63, q0 = t >> 6;
#pragma unroll
    for (int i = 0; i < 16; ++i) {
        const int q = q0 * 16 + i;
        rW[hB + (size_t)(qh * 64 + q) * 64 + kw] =
            Us[q + 63 - kw][q] * LOG2E;
    }
}

// ---------------------------------------------------------------------------
// Flash attention, S^T formulation, TK=128 (2 sub-tiles/iter), no-max softmax.
// Block = (q-tile 64, head), 4 waves. Each lane owns ONE softmax row.
// P C->A transform: v_permlane{32,16}_swap (VALU pipe) instead of ds_bpermute
// -- the transform was the largest LDS-pipe consumer (32 of 72 LDS ops/iter).
// Verified mapping: {av.x,av.z} = permlane16_swap(permlane32_swap(A0,B0)),
// identical element movement to the proven shfl path (kept as fallback).
// ---------------------------------------------------------------------------
__global__ __launch_bounds__(256, 3) void flash_mfma_kernel(
    const short* __restrict__ qbh, const short* __restrict__ kbh,
    const short* __restrict__ vbT, const float* __restrict__ rW,
    const float* __restrict__ rph, short* __restrict__ aob)
{
    __shared__ __align__(16) short Ks[128][68];   // [tok][d], pad 4
    __shared__ __align__(16) short Vt[64][132];   // [d][tok], pad 4
    __shared__ float relHs[64][65];               // [kh][q-local] (log2e)

    const int t = threadIdx.x;
    const int qt = blockIdx.x, head = blockIdx.y;
    const int row0 = qt * 64;
    const int lane = t & 63, w = t >> 6;
    const int l15 = lane & 15, l4 = lane >> 4;
    const size_t hB = (size_t)head * NTOK * 64;
    const float SC = 0.125f * LOG2E;

    // Q as B-fragments (n = q-row = 16w + l15), k = s*32 + l4*8 + j
    bf8v bQ[2];
    {
        const short* qsrc = qbh + hB + (size_t)(row0 + 16 * w + l15) * 64;
#pragma unroll
        for (int s = 0; s < 2; ++s)
            bQ[s] = *(const bf8v*)(qsrc + s * 32 + l4 * 8);
    }
    // relW preload (LOG2E-scaled): element (q=l15, kw=16nt+4l4+r)
    float rw[4][4];
#pragma unroll
    for (int nt = 0; nt < 4; ++nt)
#pragma unroll
        for (int r = 0; r < 4; ++r)
            rw[nt][r] = rW[hB + (size_t)(row0 + 16 * w + l15) * 64 +
                           nt * 16 + l4 * 4 + r];

    // stage reversed rph slice (x LOG2E) into Ks rows 0..63 for relH GEMM
    {
        const int rr = t >> 2, d0 = (t & 3) * 16;
        const float* src = rph + (size_t)(qt + 63 - rr) * 64 + d0;
        float4 a0 = *(const float4*)(src);
        float4 a1 = *(const float4*)(src + 4);
        float4 a2 = *(const float4*)(src + 8);
        float4 a3 = *(const float4*)(src + 12);
        a0.x *= LOG2E; a0.y *= LOG2E; a0.z *= LOG2E; a0.w *= LOG2E;
        a1.x *= LOG2E; a1.y *= LOG2E; a1.z *= LOG2E; a1.w *= LOG2E;
        a2.x *= LOG2E; a2.y *= LOG2E; a2.z *= LOG2E; a2.w *= LOG2E;
        a3.x *= LOG2E; a3.y *= LOG2E; a3.z *= LOG2E; a3.w *= LOG2E;
        *(bf8v*)&Ks[rr][d0] = pack8(a0, a1);
        *(bf8v*)&Ks[rr][d0 + 8] = pack8(a2, a3);
    }
    // prefetch K/V tile 0 into registers (TK=128: 2 K rows + 64B of V^T each)
    const int sx = t >> 2;            // K token row (and V d-row)
    const int sck = (t & 3) * 16;     // K d-offset (shorts)
    const int scv = (t & 3) * 32;     // V token-offset (shorts)
    const short* kptr = kbh + hB + (size_t)sx * 64 + sck;
    const short* vptr = vbT + ((size_t)head * 64 + sx) * NTOK + scv;
    bf8v kpf[4], vpf[4];
    kpf[0] = *(const bf8v*)(kptr);
    kpf[1] = *(const bf8v*)(kptr + 8);
    kpf[2] = *(const bf8v*)(kptr + 64 * 64);
    kpf[3] = *(const bf8v*)(kptr + 64 * 64 + 8);
    vpf[0] = *(const bf8v*)(vptr);
    vpf[1] = *(const bf8v*)(vptr + 8);
    vpf[2] = *(const bf8v*)(vptr + 16);
    vpf[3] = *(const bf8v*)(vptr + 24);

    __syncthreads();
    // relHs = rph_rev · Q^T  (m = kh, n = q-local)
#pragma unroll
    for (int nt = 0; nt < 4; ++nt) {
        f4v c = {0.f, 0.f, 0.f, 0.f};
#pragma unroll
        for (int s = 0; s < 2; ++s)
            c = __builtin_amdgcn_mfma_f32_16x16x32_bf16(
                *(const bf8v*)&Ks[nt * 16 + l15][s * 32 + l4 * 8], bQ[s], c,
                0, 0, 0);
#pragma unroll
        for (int r = 0; r < 4; ++r)
            relHs[nt * 16 + l4 * 4 + r][16 * w + l15] = c[r];
    }

    f4v O[4] = {{0.f, 0.f, 0.f, 0.f}, {0.f, 0.f, 0.f, 0.f},
                {0.f, 0.f, 0.f, 0.f}, {0.f, 0.f, 0.f, 0.f}};
    float lsum = 0.f;

#ifndef HAVE_PERMLANE_SWAP
    const int xsel = ((lane >> 4) & 1) * 32 + l15;      // transform src lane
    const bool lo32 = (lane < 32);
#endif

    for (int it = 0; it < 32; ++it) {
        __syncthreads();
        *(bf8v*)&Ks[sx][sck] = kpf[0];
        *(bf8v*)&Ks[sx][sck + 8] = kpf[1];
        *(bf8v*)&Ks[sx + 64][sck] = kpf[2];
        *(bf8v*)&Ks[sx + 64][sck + 8] = kpf[3];
        *(bf8v*)&Vt[sx][scv] = vpf[0];
        *(bf8v*)&Vt[sx][scv + 8] = vpf[1];
        *(bf8v*)&Vt[sx][scv + 16] = vpf[2];
        *(bf8v*)&Vt[sx][scv + 24] = vpf[3];
        {
            const int itn = (it < 31) ? it + 1 : 31;
            const short* kp = kptr + (size_t)itn * 128 * 64;
            const short* vp = vptr + itn * 128;
            kpf[0] = *(const bf8v*)kp;
            kpf[1] = *(const bf8v*)(kp + 8);
            kpf[2] = *(const bf8v*)(kp + 64 * 64);
            kpf[3] = *(const bf8v*)(kp + 64 * 64 + 8);
            vpf[0] = *(const bf8v*)vp;
            vpf[1] = *(const bf8v*)(vp + 8);
            vpf[2] = *(const bf8v*)(vp + 16);
            vpf[3] = *(const bf8v*)(vp + 24);
        }
        __syncthreads();

        // S^T for both sub-tiles (independent chains)
        f4v accA[4] = {{0.f, 0.f, 0.f, 0.f}, {0.f, 0.f, 0.f, 0.f},
                       {0.f, 0.f, 0.f, 0.f}, {0.f, 0.f, 0.f, 0.f}};
        f4v accB[4] = {{0.f, 0.f, 0.f, 0.f}, {0.f, 0.f, 0.f, 0.f},
                       {0.f, 0.f, 0.f, 0.f}, {0.f, 0.f, 0.f, 0.f}};
#pragma unroll
        for (int s = 0; s < 2; ++s)
#pragma unroll
            for (int nt = 0; nt < 4; ++nt) {
                accA[nt] = __builtin_amdgcn_mfma_f32_16x16x32_bf16(
                    *(const bf8v*)&Ks[nt * 16 + l15][s * 32 + l4 * 8], bQ[s],
                    accA[nt], 0, 0, 0);
                accB[nt] = __builtin_amdgcn_mfma_f32_16x16x32_bf16(
                    *(const bf8v*)&Ks[64 + nt * 16 + l15][s * 32 + l4 * 8],
                    bQ[s], accB[nt], 0, 0, 0);
            }

        const float rhA = relHs[2 * it][16 * w + l15];
        const float rhB = relHs[2 * it + 1][16 * w + l15];

        // e = exp2(SC*acc + (rw + rh)); no max subtraction (exact rescale)
        float eA[4][4], eB[4][4];
#pragma unroll
        for (int nt = 0; nt < 4; ++nt)
#pragma unroll
            for (int r = 0; r < 4; ++r) {
                eA[nt][r] = __builtin_amdgcn_exp2f(
                    fmaf(accA[nt][r], SC, rw[nt][r] + rhA));
                eB[nt][r] = __builtin_amdgcn_exp2f(
                    fmaf(accB[nt][r], SC, rw[nt][r] + rhB));
            }
        // deferred l: per-lane partial sum (reduced once in epilogue)
        {
            float sA = ((eA[0][0] + eA[0][1]) + (eA[0][2] + eA[0][3])) +
                       ((eA[1][0] + eA[1][1]) + (eA[1][2] + eA[1][3])) +
                       ((eA[2][0] + eA[2][1]) + (eA[2][2] + eA[2][3])) +
                       ((eA[3][0] + eA[3][1]) + (eA[3][2] + eA[3][3]));
            float sB = ((eB[0][0] + eB[0][1]) + (eB[0][2] + eB[0][3])) +
                       ((eB[1][0] + eB[1][1]) + (eB[1][2] + eB[1][3])) +
                       ((eB[2][0] + eB[2][1]) + (eB[2][2] + eB[2][3])) +
                       ((eB[3][0] + eB[3][1]) + (eB[3][2] + eB[3][3]));
            lsum += sA + sB;
        }

        // pack P, C->A quad-permute transform, PV accumulate per sub-tile
#pragma unroll
        for (int half = 0; half < 2; ++half) {
            float (*e)[4] = half ? eB : eA;
            unsigned pk[4][2];
#pragma unroll
            for (int nt = 0; nt < 4; ++nt) {
                pk[nt][0] = pkbf(e[nt][1], e[nt][0]);
                pk[nt][1] = pkbf(e[nt][3], e[nt][2]);
            }
            bf8v aP[2];
#ifdef HAVE_PERMLANE_SWAP
#pragma unroll
            for (int s = 0; s < 2; ++s) {
                // {av.x, av.z} = plane16_swap(plane32_swap(A0, B0))
                auto ta = __builtin_amdgcn_permlane32_swap(
                    pk[2 * s][0], pk[2 * s + 1][0], false, false);
                auto tb = __builtin_amdgcn_permlane16_swap(
                    ta[0], ta[1], false, false);
                auto tc = __builtin_amdgcn_permlane32_swap(
                    pk[2 * s][1], pk[2 * s + 1][1], false, false);
                auto td = __builtin_amdgcn_permlane16_swap(
                    tc[0], tc[1], false, false);
                int4 av;
                av.x = (int)tb[0];
                av.y = (int)td[0];
                av.z = (int)tb[1];
                av.w = (int)td[1];
                union { int4 i; bf8v v; } u; u.i = av;
                aP[s] = u.v;
            }
#else
#pragma unroll
            for (int s = 0; s < 2; ++s) {
                const int x0 = __shfl((int)pk[2 * s][0], xsel);
                const int y0 = __shfl((int)pk[2 * s + 1][0], xsel);
                const int x1 = __shfl((int)pk[2 * s][1], xsel);
                const int y1 = __shfl((int)pk[2 * s + 1][1], xsel);
                const int x2 = __shfl((int)pk[2 * s][0], xsel + 16);
                const int y2 = __shfl((int)pk[2 * s + 1][0], xsel + 16);
                const int x3 = __shfl((int)pk[2 * s][1], xsel + 16);
                const int y3 = __shfl((int)pk[2 * s + 1][1], xsel + 16);
                int4 av;
                av.x = lo32 ? x0 : y0;
                av.y = lo32 ? x1 : y1;
                av.z = lo32 ? x2 : y2;
                av.w = lo32 ? x3 : y3;
                union { int4 i; bf8v v; } u; u.i = av;
                aP[s] = u.v;
            }
#endif
#pragma unroll
            for (int s = 0; s < 2; ++s)
#pragma unroll
                for (int nt = 0; nt < 4; ++nt)
                    O[nt] = __builtin_amdgcn_mfma_f32_16x16x32_bf16(
                        aP[s],
                        *(const bf8v*)&Vt[nt * 16 + l15]
                                         [half * 64 + s * 32 + l4 * 8],
                        O[nt], 0, 0, 0);
        }
    }

    // epilogue: reduce l across the 4 token-partitions, normalize, store
    lsum += __shfl_xor(lsum, 16);
    lsum += __shfl_xor(lsum, 32);
    const float linv = 1.0f / lsum;
    float li[4];
#pragma unroll
    for (int r = 0; r < 4; ++r) li[r] = __shfl(linv, 4 * l4 + r);
#pragma unroll
    for (int r = 0; r < 4; ++r) {
        const int row = row0 + 16 * w + l4 * 4 + r;
#pragma unroll
        for (int nt = 0; nt < 4; ++nt)
            aob[(size_t)row * 768 + head * 64 + nt * 16 + l15] =
                (short)f2bf(O[nt][r] * li[r]);
    }
}

// ---------------------------------------------------------------------------
// proj GEMM (MFMA bf16): out[m][n] = aob[m][k] @ pwT[n][k]^T + bias[n] (fp32)
// ---------------------------------------------------------------------------
__global__ __launch_bounds__(256) void proj_mfma_kernel(
    const short* __restrict__ aoh, const short* __restrict__ pwT,
    const float* __restrict__ bias, float* __restrict__ out)
{
    __shared__ __align__(16) short As[128 * 32];
    __shared__ __align__(16) short Bs[128 * 32];
    const int t = threadIdx.x;
    const int w = t >> 6, lane = t & 63;
    const int l15 = lane & 15, l4 = lane >> 4;
    const int wr = w >> 1, wc = w & 1;
    const int row0 = blockIdx.y * 128, col0 = blockIdx.x * 128;
    const int ldr = lane >> 2;
    const int ldk = (lane & 3) * 8;

    f4v acc[4][4] = {};
    const short* aBase = aoh + (size_t)(row0 + w * 32 + ldr) * 768 + ldk;
    const short* bBase = pwT + (size_t)(col0 + w * 32 + ldr) * 768 + ldk;

    for (int kk = 0; kk < 768; kk += 32) {
        __syncthreads();
#pragma unroll
        for (int c = 0; c < 2; ++c) {
            gload_lds16(aBase + (size_t)c * 16 * 768 + kk,
                        &As[(w * 32 + c * 16) * 32]);
            gload_lds16(bBase + (size_t)c * 16 * 768 + kk,
                        &Bs[(w * 32 + c * 16) * 32]);
        }
        __syncthreads();
        bf8v af[4], bg[4];
#pragma unroll
        for (int i = 0; i < 4; ++i) {
            af[i] = *(const bf8v*)&As[(wr * 64 + 16 * i + l15) * 32 + l4 * 8];
            bg[i] = *(const bf8v*)&Bs[(wc * 64 + 16 * i + l15) * 32 + l4 * 8];
        }
#pragma unroll
        for (int i = 0; i < 4; ++i)
#pragma unroll
            for (int j = 0; j < 4; ++j)
                acc[i][j] = __builtin_amdgcn_mfma_f32_16x16x32_bf16(
                    af[i], bg[j], acc[i][j], 0, 0, 0);
    }

#pragma unroll
    for (int j = 0; j < 4; ++j) {
        const int n = col0 + wc * 64 + 16 * j + l15;
        const float bv = bias[n];
#pragma unroll
        for (int i = 0; i < 4; ++i) {
            const int m = row0 + wr * 64 + 16 * i + l4 * 4;
#pragma unroll
            for (int r = 0; r < 4; ++r)
                out[(size_t)(m + r) * 768 + n] = acc[i][j][r] + bv;
        }
    }
}

// ---------------------------------------------------------------------------
extern "C" void kernel_launch(void* const* d_in, const int* in_sizes, int n_in,
                              void* d_out, int out_size, void* d_ws,
                              size_t ws_size, hipStream_t stream)
{
    (void)in_sizes; (void)n_in; (void)out_size; (void)ws_size;
    const float* x    = (const float*)d_in[0];
    const float* qkvw = (const float*)d_in[1];
    const float* qkvb = (const float*)d_in[2];
    const float* pw   = (const float*)d_in[3];
    const float* pb   = (const float*)d_in[4];
    const float* rph  = (const float*)d_in[5];
    const float* rpw  = (const float*)d_in[6];
    float* out = (float*)d_out;

    const size_t S = (size_t)NHEADS * NTOK * 64;  // 3,145,728 (= 4096*768)
    float* rW   = (float*)d_ws;          // S fp32 relW (LOG2E-scaled)
    short* qbh  = (short*)(rW + S);      // S bf16   q  [h][tok][d]
    short* kbh  = qbh + S;               // S bf16   k  [h][tok][d]
    short* vbT  = kbh + S;               // S bf16   v^T [h][d][tok]
    short* xh   = vbT + S;               // S bf16   x  [tok][c]
    short* aob  = xh + S;                // S bf16   attn out [tok][c]
    short* wqkvT = aob + S;              // 2304*768 bf16
    short* pwT  = wqkvT + (size_t)2304 * 768;  // 768*768 bf16
    short* rpwb = pwT + (size_t)768 * 768;     // 128*64 bf16 rel_pos_w
    // total ~48.8 MB

    cvt_kernel<<<dim3(1536), 256, 0, stream>>>(x, xh);
    tcvt_kernel<<<dim3(36, 12), 256, 0, stream>>>(qkvw, wqkvT, 768, 2304);
    tcvt_kernel<<<dim3(12, 12), 256, 0, stream>>>(pw, pwT, 768, 768);
    cvt_rpw_kernel<<<dim3(32), 256, 0, stream>>>(rpw, rpwb);
    qkv_mfma_kernel<<<dim3(18, 32), 256, 0, stream>>>(xh, wqkvT, qkvb,
                                                      qbh, kbh, vbT);
    relu_kernel<<<dim3(NHEADS, 64), 256, 0, stream>>>(qbh, rpwb, rW);
    flash_mfma_kernel<<<dim3(64, NHEADS), 256, 0, stream>>>(qbh, kbh, vbT, rW,
                                                            rph, aob);
    proj_mfma_kernel<<<dim3(6, 32), 256, 0, stream>>>(aob, pwT, pb, out);
}

// Round 10
// 230.869 us; speedup vs baseline: 1.7246x; 1.0706x over previous
//
#include <hip/hip_runtime.h>
#include <math.h>

// Problem constants: B=1, H=W=64 (N=4096), C=768, 12 heads x hd=64.
#define NHEADS 12
#define NTOK 4096
#define LOG2E 1.44269504f

typedef __attribute__((ext_vector_type(8))) short bf8v;    // 8 x bf16
typedef __attribute__((ext_vector_type(4))) float f4v;     // 16x16 C/D frag
typedef __attribute__((ext_vector_type(16))) float f16v;   // 32x32 C/D frag

__device__ __forceinline__ unsigned short f2bf(float f) {
  unsigned int u = __float_as_uint(f);
  u += 0x7fffu + ((u >> 16) & 1u);   // RNE
  return (unsigned short)(u >> 16);
}
__device__ __forceinline__ float bf2f(unsigned short h) {
  return __uint_as_float(((unsigned int)h) << 16);
}
__device__ __forceinline__ bf8v pack8(float4 a, float4 b) {
  bf8v v;
  v[0] = (short)f2bf(a.x); v[1] = (short)f2bf(a.y);
  v[2] = (short)f2bf(a.z); v[3] = (short)f2bf(a.w);
  v[4] = (short)f2bf(b.x); v[5] = (short)f2bf(b.y);
  v[6] = (short)f2bf(b.z); v[7] = (short)f2bf(b.w);
  return v;
}
// pack two f32 (round via +0x8000) into (hi|lo) bf16 pair
__device__ __forceinline__ unsigned pkbf(float hi, float lo) {
  return __builtin_amdgcn_perm(__float_as_uint(hi) + 0x8000u,
                               __float_as_uint(lo) + 0x8000u, 0x07060302u);
}

// ---------------------------------------------------------------------------
// cvt: fp32 -> bf16 elementwise (x), 8 elems/thread
// ---------------------------------------------------------------------------
__global__ __launch_bounds__(256) void cvt_kernel(
    const float* __restrict__ in, short* __restrict__ out)
{
    const size_t i = ((size_t)blockIdx.x * 256 + threadIdx.x) * 8;
    float4 a = *(const float4*)(in + i);
    float4 b = *(const float4*)(in + i + 4);
    *(bf8v*)(out + i) = pack8(a, b);
}

// ---------------------------------------------------------------------------
// cvt_rpw: rel_pos_w fp32 [127][64] -> bf16 [128][64] (row 127 zeroed)
// ---------------------------------------------------------------------------
__global__ __launch_bounds__(256) void cvt_rpw_kernel(
    const float* __restrict__ in, short* __restrict__ out)
{
    const int idx = blockIdx.x * 256 + threadIdx.x;   // grid 32 -> 8192
    const float v = (idx < 127 * 64) ? in[idx] : 0.f;
    out[idx] = (short)f2bf(v);
}

// ---------------------------------------------------------------------------
// tcvt: fp32 in[R][C] -> bf16 out[C][R] (64x64 LDS tiles)
// ---------------------------------------------------------------------------
__global__ __launch_bounds__(256) void tcvt_kernel(
    const float* __restrict__ in, short* __restrict__ out, int R, int C)
{
    __shared__ float Ts[64][65];
    const int bc = blockIdx.x * 64, br = blockIdx.y * 64, t = threadIdx.x;
    {
        const int r = t >> 2, c0 = (t & 3) * 16;
        const float* src = in + (size_t)(br + r) * C + bc + c0;
#pragma unroll
        for (int i = 0; i < 4; ++i) {
            float4 a = *(const float4*)(src + 4 * i);
            Ts[r][c0 + 4 * i + 0] = a.x;
            Ts[r][c0 + 4 * i + 1] = a.y;
            Ts[r][c0 + 4 * i + 2] = a.z;
            Ts[r][c0 + 4 * i + 3] = a.w;
        }
    }
    __syncthreads();
    const int c = t >> 2, r0 = (t & 3) * 16;
    short* dst = out + (size_t)(bc + c) * R + br + r0;
#pragma unroll
    for (int p = 0; p < 2; ++p) {
        bf8v v;
#pragma unroll
        for (int i = 0; i < 8; ++i) v[i] = (short)f2bf(Ts[r0 + p * 8 + i][c]);
        *(bf8v*)(dst + p * 8) = v;
    }
}

// ---------------------------------------------------------------------------
// QKV GEMM (MFMA bf16): C[m][n] = xh[m][k] @ wT[n][k]^T + bias[n]
// ---------------------------------------------------------------------------
__device__ __forceinline__ void gload_lds16(const void* g, void* l) {
  __builtin_amdgcn_global_load_lds(
      (const __attribute__((address_space(1))) void*)g,
      (__attribute__((address_space(3))) void*)l, 16, 0, 0);
}

__global__ __launch_bounds__(256) void qkv_mfma_kernel(
    const short* __restrict__ xh, const short* __restrict__ wT,
    const float* __restrict__ bias, short* __restrict__ qbh,
    short* __restrict__ kbh, short* __restrict__ vbT)
{
    __shared__ __align__(16) short As[128 * 32];
    __shared__ __align__(16) short Bs[128 * 32];
    const int t = threadIdx.x;
    const int w = t >> 6, lane = t & 63;
    const int l15 = lane & 15, l4 = lane >> 4;
    const int wr = w >> 1, wc = w & 1;
    const int row0 = blockIdx.y * 128, col0 = blockIdx.x * 128;
    const int ldr = lane >> 2;
    const int ldk = (lane & 3) * 8;

    f4v acc[4][4] = {};
    const short* aBase = xh + (size_t)(row0 + w * 32 + ldr) * 768 + ldk;
    const short* bBase = wT + (size_t)(col0 + w * 32 + ldr) * 768 + ldk;

    for (int kk = 0; kk < 768; kk += 32) {
        __syncthreads();
#pragma unroll
        for (int c = 0; c < 2; ++c) {
            gload_lds16(aBase + (size_t)c * 16 * 768 + kk,
                        &As[(w * 32 + c * 16) * 32]);
            gload_lds16(bBase + (size_t)c * 16 * 768 + kk,
                        &Bs[(w * 32 + c * 16) * 32]);
        }
        __syncthreads();
        bf8v af[4], bg[4];
#pragma unroll
        for (int i = 0; i < 4; ++i) {
            af[i] = *(const bf8v*)&As[(wr * 64 + 16 * i + l15) * 32 + l4 * 8];
            bg[i] = *(const bf8v*)&Bs[(wc * 64 + 16 * i + l15) * 32 + l4 * 8];
        }
#pragma unroll
        for (int i = 0; i < 4; ++i)
#pragma unroll
            for (int j = 0; j < 4; ++j)
                acc[i][j] = __builtin_amdgcn_mfma_f32_16x16x32_bf16(
                    af[i], bg[j], acc[i][j], 0, 0, 0);
    }

#pragma unroll
    for (int j = 0; j < 4; ++j) {
        const int n = col0 + wc * 64 + 16 * j + l15;
        const int s = n / 768;            // block-uniform (768 = 6*128)
        const int rm = n - s * 768;
        const int h = rm >> 6, d = rm & 63;
        const float bv = bias[n];
        if (s == 2) {
            short* vdst = vbT + (size_t)(h * 64 + d) * NTOK;
#pragma unroll
            for (int i = 0; i < 4; ++i) {
                const int m = row0 + wr * 64 + 16 * i + l4 * 4;
                short4 pv;
                pv.x = (short)f2bf(acc[i][j][0] + bv);
                pv.y = (short)f2bf(acc[i][j][1] + bv);
                pv.z = (short)f2bf(acc[i][j][2] + bv);
                pv.w = (short)f2bf(acc[i][j][3] + bv);
                *(short4*)(vdst + m) = pv;
            }
        } else {
            short* dst = (s == 0) ? qbh : kbh;
#pragma unroll
            for (int i = 0; i < 4; ++i) {
                const int m = row0 + wr * 64 + 16 * i + l4 * 4;
#pragma unroll
                for (int r = 0; r < 4; ++r)
                    dst[((size_t)h * NTOK + m + r) * 64 + d] =
                        (short)f2bf(acc[i][j][r] + bv);
            }
        }
    }
}

// ---------------------------------------------------------------------------
// relu: U[j][qw] = sum_d rpwb[j][d] * Q[h][qh*64+qw][d]  (MFMA, per (h,qh))
// then rWb[h][qh*64+qw][kw] = bf16( LOG2E * U[qw+63-kw][qw] )
// ---------------------------------------------------------------------------
__global__ __launch_bounds__(256) void relu_kernel(
    const short* __restrict__ qbh, const short* __restrict__ rpwb,
    short* __restrict__ rWb)
{
    __shared__ float Us[128][65];
    const int h = blockIdx.x, qh = blockIdx.y;
    const int t = threadIdx.x, w = t >> 6, lane = t & 63;
    const int l15 = lane & 15, l4 = lane >> 4;
    const size_t hB = (size_t)h * NTOK * 64;

    bf8v bq[4][2];
#pragma unroll
    for (int nt = 0; nt < 4; ++nt) {
        const short* qs = qbh + hB + (size_t)(qh * 64 + nt * 16 + l15) * 64;
#pragma unroll
        for (int s = 0; s < 2; ++s)
            bq[nt][s] = *(const bf8v*)(qs + s * 32 + l4 * 8);
    }
    bf8v aw[2][2];
#pragma unroll
    for (int mi = 0; mi < 2; ++mi) {
        const short* as = rpwb + (size_t)((w * 2 + mi) * 16 + l15) * 64;
#pragma unroll
        for (int s = 0; s < 2; ++s)
            aw[mi][s] = *(const bf8v*)(as + s * 32 + l4 * 8);
    }
    f4v U[2][4] = {};
#pragma unroll
    for (int mi = 0; mi < 2; ++mi)
#pragma unroll
        for (int nt = 0; nt < 4; ++nt)
#pragma unroll
            for (int s = 0; s < 2; ++s)
                U[mi][nt] = __builtin_amdgcn_mfma_f32_16x16x32_bf16(
                    aw[mi][s], bq[nt][s], U[mi][nt], 0, 0, 0);
#pragma unroll
    for (int mi = 0; mi < 2; ++mi)
#pragma unroll
        for (int nt = 0; nt < 4; ++nt)
#pragma unroll
            for (int r = 0; r < 4; ++r)
                Us[(w * 2 + mi) * 16 + l4 * 4 + r][nt * 16 + l15] =
                    U[mi][nt][r];
    __syncthreads();
    const int kw = t & 63, q0 = t >> 6;
#pragma unroll
    for (int i = 0; i < 16; ++i) {
        const int q = q0 * 16 + i;
        rWb[hB + (size_t)(qh * 64 + q) * 64 + kw] =
            (short)f2bf(Us[q + 63 - kw][q] * LOG2E);
    }
}

// ---------------------------------------------------------------------------
// Flash attention v5: 32x32x16 MFMA. Block = (q-tile 64, head), 4 waves:
// wave w -> (qh2=w&1: 32-q half, th=w>>1: 64-token half of the 128-tile).
// S^T = K.Q^T per wave: C col = q = lane&31 (one softmax row per lane),
// rows = tokens (reg&3)+8*(reg>>2)+4*(lane>>5). PV A-frag from C via
// 2x permlane32_swap per k-step (pure VALU). No-max softmax (exact).
// Epilogue combines the two token-half waves via LDS.
// Staging identical to R9 (register prefetch -> padded Ks/Vt).
// ---------------------------------------------------------------------------
__global__ __launch_bounds__(256, 3) void flash_mfma_kernel(
    const short* __restrict__ qbh, const short* __restrict__ kbh,
    const short* __restrict__ vbT, const short* __restrict__ rWb,
    const float* __restrict__ rph, short* __restrict__ aob)
{
    __shared__ __align__(16) short Ks[128][68];   // [tok][d], pad 4
    __shared__ __align__(16) short Vt[64][132];   // [d][tok], pad 4
    __shared__ float relHs[64][65];               // [kh][q-local] (log2e)

    const int t = threadIdx.x;
    const int qt = blockIdx.x, head = blockIdx.y;
    const int row0 = qt * 64;
    const int lane = t & 63, w = t >> 6;
    const int qh2 = w & 1, th = w >> 1;
    const int l31 = lane & 31, hf = lane >> 5;
    const size_t hB = (size_t)head * NTOK * 64;
    const float SC = 0.125f * LOG2E;

    // Q as 32x32 B-fragments: B[k=d][n=q], lane n=l31, k = 8*hf + j
    const int q = row0 + qh2 * 32 + l31;
    bf8v bQ[4];
    {
        const short* qsrc = qbh + hB + (size_t)q * 64;
#pragma unroll
        for (int ks = 0; ks < 4; ++ks)
            bQ[ks] = *(const bf8v*)(qsrc + ks * 16 + hf * 8);
    }
    // relW packed bf16 (LOG2E-scaled): rwp[t32][g] = kw t32*32+8g+4hf+{0..3}
    uint2 rwp[2][4];
    {
        const short* rsrc = rWb + hB + (size_t)q * 64;
#pragma unroll
        for (int t32 = 0; t32 < 2; ++t32)
#pragma unroll
            for (int g = 0; g < 4; ++g)
                rwp[t32][g] =
                    *(const uint2*)(rsrc + t32 * 32 + 8 * g + 4 * hf);
    }

    // stage reversed rph slice (x LOG2E) into Ks rows 0..63 for relH GEMM
    {
        const int rr = t >> 2, d0 = (t & 3) * 16;
        const float* src = rph + (size_t)(qt + 63 - rr) * 64 + d0;
        float4 a0 = *(const float4*)(src);
        float4 a1 = *(const float4*)(src + 4);
        float4 a2 = *(const float4*)(src + 8);
        float4 a3 = *(const float4*)(src + 12);
        a0.x *= LOG2E; a0.y *= LOG2E; a0.z *= LOG2E; a0.w *= LOG2E;
        a1.x *= LOG2E; a1.y *= LOG2E; a1.z *= LOG2E; a1.w *= LOG2E;
        a2.x *= LOG2E; a2.y *= LOG2E; a2.z *= LOG2E; a2.w *= LOG2E;
        a3.x *= LOG2E; a3.y *= LOG2E; a3.z *= LOG2E; a3.w *= LOG2E;
        *(bf8v*)&Ks[rr][d0] = pack8(a0, a1);
        *(bf8v*)&Ks[rr][d0 + 8] = pack8(a2, a3);
    }
    // prefetch K/V tile 0 into registers (identical to R9)
    const int sx = t >> 2;            // K token row (and V d-row)
    const int sck = (t & 3) * 16;     // K d-offset (shorts)
    const int scv = (t & 3) * 32;     // V token-offset (shorts)
    const short* kptr = kbh + hB + (size_t)sx * 64 + sck;
    const short* vptr = vbT + ((size_t)head * 64 + sx) * NTOK + scv;
    bf8v kpf[4], vpf[4];
    kpf[0] = *(const bf8v*)(kptr);
    kpf[1] = *(const bf8v*)(kptr + 8);
    kpf[2] = *(const bf8v*)(kptr + 64 * 64);
    kpf[3] = *(const bf8v*)(kptr + 64 * 64 + 8);
    vpf[0] = *(const bf8v*)(vptr);
    vpf[1] = *(const bf8v*)(vptr + 8);
    vpf[2] = *(const bf8v*)(vptr + 16);
    vpf[3] = *(const bf8v*)(vptr + 24);

    __syncthreads();
    // relH GEMM (32x32): A = rph_rev rows (kh), B = bQ. Wave th covers
    // kh-tile th*32; result row kh = th*32 + (reg&3)+8*(reg>>2)+4*hf.
    {
        f16v c = {};
#pragma unroll
        for (int ks = 0; ks < 4; ++ks)
            c = __builtin_amdgcn_mfma_f32_32x32x16_bf16(
                *(const bf8v*)&Ks[th * 32 + l31][ks * 16 + hf * 8], bQ[ks],
                c, 0, 0, 0);
#pragma unroll
        for (int reg = 0; reg < 16; ++reg)
            relHs[th * 32 + (reg & 3) + 8 * (reg >> 2) + 4 * hf]
                 [qh2 * 32 + l31] = c[reg];
    }

    f16v O[2] = {{}, {}};   // ntile: d = ntile*32+l31; rows q (C layout)
    float lsum = 0.f;

    for (int it = 0; it < 32; ++it) {
        __syncthreads();
        *(bf8v*)&Ks[sx][sck] = kpf[0];
        *(bf8v*)&Ks[sx][sck + 8] = kpf[1];
        *(bf8v*)&Ks[sx + 64][sck] = kpf[2];
        *(bf8v*)&Ks[sx + 64][sck + 8] = kpf[3];
        *(bf8v*)&Vt[sx][scv] = vpf[0];
        *(bf8v*)&Vt[sx][scv + 8] = vpf[1];
        *(bf8v*)&Vt[sx][scv + 16] = vpf[2];
        *(bf8v*)&Vt[sx][scv + 24] = vpf[3];
        {
            const int itn = (it < 31) ? it + 1 : 31;
            const short* kp = kptr + (size_t)itn * 128 * 64;
            const short* vp = vptr + itn * 128;
            kpf[0] = *(const bf8v*)kp;
            kpf[1] = *(const bf8v*)(kp + 8);
            kpf[2] = *(const bf8v*)(kp + 64 * 64);
            kpf[3] = *(const bf8v*)(kp + 64 * 64 + 8);
            vpf[0] = *(const bf8v*)vp;
            vpf[1] = *(const bf8v*)(vp + 8);
            vpf[2] = *(const bf8v*)(vp + 16);
            vpf[3] = *(const bf8v*)(vp + 24);
        }
        __syncthreads();

        // S^T: A = K tokens (this wave's half), B = bQ
        f16v acc[2] = {{}, {}};
#pragma unroll
        for (int ks = 0; ks < 4; ++ks)
#pragma unroll
            for (int t32 = 0; t32 < 2; ++t32)
                acc[t32] = __builtin_amdgcn_mfma_f32_32x32x16_bf16(
                    *(const bf8v*)&Ks[th * 64 + t32 * 32 + l31]
                                     [ks * 16 + hf * 8],
                    bQ[ks], acc[t32], 0, 0, 0);

        const float rh = relHs[2 * it + th][qh2 * 32 + l31];

        // e = exp2(SC*acc + rw + rh); pack to bf16 pairs per 4-row group
        unsigned xg[2][4], yg[2][4];
#pragma unroll
        for (int t32 = 0; t32 < 2; ++t32) {
            float sub = 0.f;
#pragma unroll
            for (int g = 0; g < 4; ++g) {
                const unsigned u0 = rwp[t32][g].x;
                const unsigned u1 = rwp[t32][g].y;
                const float b0 = __uint_as_float(u0 << 16) + rh;
                const float b1 = __uint_as_float(u0 & 0xffff0000u) + rh;
                const float b2 = __uint_as_float(u1 << 16) + rh;
                const float b3 = __uint_as_float(u1 & 0xffff0000u) + rh;
                const float e0 = __builtin_amdgcn_exp2f(
                    fmaf(acc[t32][4 * g + 0], SC, b0));
                const float e1 = __builtin_amdgcn_exp2f(
                    fmaf(acc[t32][4 * g + 1], SC, b1));
                const float e2 = __builtin_amdgcn_exp2f(
                    fmaf(acc[t32][4 * g + 2], SC, b2));
                const float e3 = __builtin_amdgcn_exp2f(
                    fmaf(acc[t32][4 * g + 3], SC, b3));
                sub += (e0 + e1) + (e2 + e3);
                xg[t32][g] = pkbf(e1, e0);
                yg[t32][g] = pkbf(e3, e2);
            }
            lsum += sub;
        }

        // PV: A-frag via permlane32_swap pairs; B from Vt
#pragma unroll
        for (int t32 = 0; t32 < 2; ++t32)
#pragma unroll
            for (int ks2 = 0; ks2 < 2; ++ks2) {
                auto px = __builtin_amdgcn_permlane32_swap(
                    xg[t32][2 * ks2], xg[t32][2 * ks2 + 1], false, false);
                auto py = __builtin_amdgcn_permlane32_swap(
                    yg[t32][2 * ks2], yg[t32][2 * ks2 + 1], false, false);
                int4 av;
                av.x = (int)px[0];
                av.y = (int)py[0];
                av.z = (int)px[1];
                av.w = (int)py[1];
                union { int4 i; bf8v v; } u; u.i = av;
#pragma unroll
                for (int nt = 0; nt < 2; ++nt)
                    O[nt] = __builtin_amdgcn_mfma_f32_32x32x16_bf16(
                        u.v,
                        *(const bf8v*)&Vt[nt * 32 + l31]
                                         [th * 64 + t32 * 32 + ks2 * 16 +
                                          hf * 8],
                        O[nt], 0, 0, 0);
            }
    }

    // epilogue: lanes l / l+32 share q -> reduce; then combine the two
    // token-half waves (th) via LDS (reuse Ks/Vt regions), normalize, store.
    lsum += __shfl_xor(lsum, 32);
    float* OEp = (float*)&Ks[0][0];   // [qh2][32 q][64 d] fp32 = 16 KB
    float* lEp = (float*)&Vt[0][0];   // [qh2][32 q]
    __syncthreads();
    if (th == 1) {
#pragma unroll
        for (int nt = 0; nt < 2; ++nt)
#pragma unroll
            for (int reg = 0; reg < 16; ++reg) {
                const int qr = (reg & 3) + 8 * (reg >> 2) + 4 * hf;
                OEp[(size_t)(qh2 * 32 + qr) * 64 + nt * 32 + l31] =
                    O[nt][reg];
            }
        if (lane < 32) lEp[qh2 * 32 + l31] = lsum;
    }
    __syncthreads();
    if (th == 0) {
        lsum += lEp[qh2 * 32 + l31];
        const float linv = 1.0f / lsum;   // valid for q = l31 (both halves)
#pragma unroll
        for (int nt = 0; nt < 2; ++nt)
#pragma unroll
            for (int reg = 0; reg < 16; ++reg) {
                const int qr = (reg & 3) + 8 * (reg >> 2) + 4 * hf;
                const float li = __shfl(linv, qr);
                const float o =
                    O[nt][reg] +
                    OEp[(size_t)(qh2 * 32 + qr) * 64 + nt * 32 + l31];
                aob[(size_t)(row0 + qh2 * 32 + qr) * 768 + head * 64 +
                    nt * 32 + l31] = (short)f2bf(o * li);
            }
    }
}

// ---------------------------------------------------------------------------
// proj GEMM (MFMA bf16): out[m][n] = aob[m][k] @ pwT[n][k]^T + bias[n] (fp32)
// ---------------------------------------------------------------------------
__global__ __launch_bounds__(256) void proj_mfma_kernel(
    const short* __restrict__ aoh, const short* __restrict__ pwT,
    const float* __restrict__ bias, float* __restrict__ out)
{
    __shared__ __align__(16) short As[128 * 32];
    __shared__ __align__(16) short Bs[128 * 32];
    const int t = threadIdx.x;
    const int w = t >> 6, lane = t & 63;
    const int l15 = lane & 15, l4 = lane >> 4;
    const int wr = w >> 1, wc = w & 1;
    const int row0 = blockIdx.y * 128, col0 = blockIdx.x * 128;
    const int ldr = lane >> 2;
    const int ldk = (lane & 3) * 8;

    f4v acc[4][4] = {};
    const short* aBase = aoh + (size_t)(row0 + w * 32 + ldr) * 768 + ldk;
    const short* bBase = pwT + (size_t)(col0 + w * 32 + ldr) * 768 + ldk;

    for (int kk = 0; kk < 768; kk += 32) {
        __syncthreads();
#pragma unroll
        for (int c = 0; c < 2; ++c) {
            gload_lds16(aBase + (size_t)c * 16 * 768 + kk,
                        &As[(w * 32 + c * 16) * 32]);
            gload_lds16(bBase + (size_t)c * 16 * 768 + kk,
                        &Bs[(w * 32 + c * 16) * 32]);
        }
        __syncthreads();
        bf8v af[4], bg[4];
#pragma unroll
        for (int i = 0; i < 4; ++i) {
            af[i] = *(const bf8v*)&As[(wr * 64 + 16 * i + l15) * 32 + l4 * 8];
            bg[i] = *(const bf8v*)&Bs[(wc * 64 + 16 * i + l15) * 32 + l4 * 8];
        }
#pragma unroll
        for (int i = 0; i < 4; ++i)
#pragma unroll
            for (int j = 0; j < 4; ++j)
                acc[i][j] = __builtin_amdgcn_mfma_f32_16x16x32_bf16(
                    af[i], bg[j], acc[i][j], 0, 0, 0);
    }

#pragma unroll
    for (int j = 0; j < 4; ++j) {
        const int n = col0 + wc * 64 + 16 * j + l15;
        const float bv = bias[n];
#pragma unroll
        for (int i = 0; i < 4; ++i) {
            const int m = row0 + wr * 64 + 16 * i + l4 * 4;
#pragma unroll
            for (int r = 0; r < 4; ++r)
                out[(size_t)(m + r) * 768 + n] = acc[i][j][r] + bv;
        }
    }
}

// ---------------------------------------------------------------------------
extern "C" void kernel_launch(void* const* d_in, const int* in_sizes, int n_in,
                              void* d_out, int out_size, void* d_ws,
                              size_t ws_size, hipStream_t stream)
{
    (void)in_sizes; (void)n_in; (void)out_size; (void)ws_size;
    const float* x    = (const float*)d_in[0];
    const float* qkvw = (const float*)d_in[1];
    const float* qkvb = (const float*)d_in[2];
    const float* pw   = (const float*)d_in[3];
    const float* pb   = (const float*)d_in[4];
    const float* rph  = (const float*)d_in[5];
    const float* rpw  = (const float*)d_in[6];
    float* out = (float*)d_out;

    const size_t S = (size_t)NHEADS * NTOK * 64;  // 3,145,728 (= 4096*768)
    short* rWb  = (short*)d_ws;          // S bf16 relW (LOG2E-scaled)
    short* qbh  = rWb + S;               // S bf16   q  [h][tok][d]
    short* kbh  = qbh + S;               // S bf16   k  [h][tok][d]
    short* vbT  = kbh + S;               // S bf16   v^T [h][d][tok]
    short* xh   = vbT + S;               // S bf16   x  [tok][c]
    short* aob  = xh + S;                // S bf16   attn out [tok][c]
    short* wqkvT = aob + S;              // 2304*768 bf16
    short* pwT  = wqkvT + (size_t)2304 * 768;  // 768*768 bf16
    short* rpwb = pwT + (size_t)768 * 768;     // 128*64 bf16 rel_pos_w
    // total ~42.5 MB

    cvt_kernel<<<dim3(1536), 256, 0, stream>>>(x, xh);
    tcvt_kernel<<<dim3(36, 12), 256, 0, stream>>>(qkvw, wqkvT, 768, 2304);
    tcvt_kernel<<<dim3(12, 12), 256, 0, stream>>>(pw, pwT, 768, 768);
    cvt_rpw_kernel<<<dim3(32), 256, 0, stream>>>(rpw, rpwb);
    qkv_mfma_kernel<<<dim3(18, 32), 256, 0, stream>>>(xh, wqkvT, qkvb,
                                                      qbh, kbh, vbT);
    relu_kernel<<<dim3(NHEADS, 64), 256, 0, stream>>>(qbh, rpwb, rWb);
    flash_mfma_kernel<<<dim3(64, NHEADS), 256, 0, stream>>>(qbh, kbh, vbT,
                                                            rWb, rph, aob);
    proj_mfma_kernel<<<dim3(6, 32), 256, 0, stream>>>(aob, pwT, pb, out);
}